// Round 1
// baseline (3459.241 us; speedup 1.0000x reference)
//
#include <hip/hip_runtime.h>
#include <hip/hip_bf16.h>

#define QLEN 512
#define MLEN 512
#define KLEN 1024
#define BSZ 8
#define DM 1024
#define NH 16
#define DH 64
#define DI 4096
#define NEGF (-1e30f)

__device__ __forceinline__ float4 ldg4(const float* p) {
    return *reinterpret_cast<const float4*>(p);
}

// ---------------- Tiled fp32 GEMM: C[M,N] = A[M,K] @ B[K,N] (+bias, +relu) ----
// 64x64 tile, BK=16, 256 threads, 4x4 per thread.
// SPLIT: A rows < splitRow come from A, rows >= splitRow from A2 (concat along M).
template<int EPI, bool SPLIT>
__global__ __launch_bounds__(256) void gemm64(
    const float* __restrict__ A, const float* __restrict__ A2, int splitRow,
    const float* __restrict__ B, const float* __restrict__ bias,
    float* __restrict__ C, int M, int N, int K)
{
    __shared__ float As[16][64];   // [k][m] transposed
    __shared__ float Bs[16][64];   // [k][n]
    const int bm = blockIdx.y * 64, bn = blockIdx.x * 64;
    const int t = threadIdx.x;
    const int tx = t & 15, ty = t >> 4;
    const int arow = t >> 2, ac4 = (t & 3) << 2;   // A tile: row 0..63, k-chunk
    const int brow = t >> 4, bc4 = (t & 15) << 2;  // B tile: k 0..15, n-chunk

    const int arowg = bm + arow;
    const float* Aptr;
    if (SPLIT) {
        Aptr = (arowg < splitRow) ? (A + (size_t)arowg * K + ac4)
                                  : (A2 + (size_t)(arowg - splitRow) * K + ac4);
    } else {
        Aptr = A + (size_t)arowg * K + ac4;
    }
    const float* Bptr = B + (size_t)brow * N + bn + bc4;

    float acc[4][4] = {};
    for (int k0 = 0; k0 < K; k0 += 16) {
        float4 av = ldg4(Aptr + k0);
        float4 bv = ldg4(Bptr + (size_t)k0 * N);
        __syncthreads();
        As[ac4 + 0][arow] = av.x;
        As[ac4 + 1][arow] = av.y;
        As[ac4 + 2][arow] = av.z;
        As[ac4 + 3][arow] = av.w;
        *reinterpret_cast<float4*>(&Bs[brow][bc4]) = bv;
        __syncthreads();
        #pragma unroll
        for (int kk = 0; kk < 16; ++kk) {
            float4 a = *reinterpret_cast<const float4*>(&As[kk][ty << 2]);
            float4 b = *reinterpret_cast<const float4*>(&Bs[kk][tx << 2]);
            float am[4] = {a.x, a.y, a.z, a.w};
            float bmv[4] = {b.x, b.y, b.z, b.w};
            #pragma unroll
            for (int i = 0; i < 4; ++i)
                #pragma unroll
                for (int j = 0; j < 4; ++j)
                    acc[i][j] += am[i] * bmv[j];
        }
    }
    #pragma unroll
    for (int i = 0; i < 4; ++i) {
        const int row = bm + (ty << 2) + i;
        float4 o;
        float* op = &o.x;
        #pragma unroll
        for (int j = 0; j < 4; ++j) {
            float v = acc[i][j];
            if constexpr (EPI >= 1) v += bias[bn + (tx << 2) + j];
            if constexpr (EPI == 2) v = fmaxf(v, 0.f);
            op[j] = v;
        }
        *reinterpret_cast<float4*>(&C[(size_t)row * N + bn + (tx << 2)]) = o;
    }
}

// ---------------- Flash-style relative attention ----------------------------
// Block = one (b, head, 64-row q-tile). 4 waves; wave w owns q-rows w*16..w*16+15.
// score[i][j] = ((q_i+rwb)·k_j + (q_i+rrb)·R[j + QLEN-1 - i]) * scale, j <= i+MLEN
// Online softmax over j; out = P@V, written to vec[(i*BSZ+b), n*DH + d].
__global__ __launch_bounds__(256) void attn_kernel(
    const float* __restrict__ heads,   // [KLEN*BSZ][3*NH*DH]
    const float* __restrict__ rhk,     // [KLEN][NH*DH]
    const float* __restrict__ rwb, const float* __restrict__ rrb,
    float* __restrict__ vec)           // [QLEN*BSZ][NH*DH]
{
    const int b = blockIdx.x >> 4;
    const int n = blockIdx.x & 15;
    const int i0 = blockIdx.y * 64;
    const int t = threadIdx.x;
    const int w = t >> 6;
    const int lane = t & 63;

    __shared__ float Qw[64][65], Qr[64][65];
    __shared__ float Ks[64][65], Vs[64][65];
    __shared__ float Rs[128][65];
    __shared__ float Ps[64][65];
    __shared__ float AlphaS[64];

    // stage Q tile with both biases applied
    #pragma unroll
    for (int rep = 0; rep < 4; ++rep) {
        int idx = t + rep * 256;
        int row = idx >> 4;
        int c4 = (idx & 15) << 2;
        float4 q = ldg4(&heads[((size_t)((MLEN + i0 + row) * BSZ + b)) * (3*NH*DH) + n*DH + c4]);
        float4 bw = ldg4(&rwb[n*DH + c4]);
        float4 br = ldg4(&rrb[n*DH + c4]);
        Qw[row][c4+0] = q.x + bw.x; Qw[row][c4+1] = q.y + bw.y;
        Qw[row][c4+2] = q.z + bw.z; Qw[row][c4+3] = q.w + bw.w;
        Qr[row][c4+0] = q.x + br.x; Qr[row][c4+1] = q.y + br.y;
        Qr[row][c4+2] = q.z + br.z; Qr[row][c4+3] = q.w + br.w;
    }

    float m_run[16], l_run[16], acc[16];
    #pragma unroll
    for (int r = 0; r < 16; ++r) { m_run[r] = NEGF; l_run[r] = 0.f; acc[r] = 0.f; }

    const int ntiles = (i0 + QLEN + 64) >> 6;
    for (int tile = 0; tile < ntiles; ++tile) {
        const int j0 = tile << 6;
        __syncthreads();   // previous tile fully consumed
        // stage K/V tiles
        #pragma unroll
        for (int rep = 0; rep < 4; ++rep) {
            int idx = t + rep * 256;
            int row = idx >> 4;
            int c4 = (idx & 15) << 2;
            size_t base = ((size_t)((j0 + row) * BSZ + b)) * (3*NH*DH) + NH*DH + n*DH + c4;
            float4 kv = ldg4(&heads[base]);
            float4 vv = ldg4(&heads[base + NH*DH]);
            Ks[row][c4+0]=kv.x; Ks[row][c4+1]=kv.y; Ks[row][c4+2]=kv.z; Ks[row][c4+3]=kv.w;
            Vs[row][c4+0]=vv.x; Vs[row][c4+1]=vv.y; Vs[row][c4+2]=vv.z; Vs[row][c4+3]=vv.w;
        }
        // stage R rows o in [obase, obase+127]; o = (j-i) + QLEN-1
        const int obase = j0 - i0 + (QLEN - 1) - 63;
        #pragma unroll
        for (int rep = 0; rep < 8; ++rep) {
            int idx = t + rep * 256;
            int row = idx >> 4;
            int c4 = (idx & 15) << 2;
            int o = obase + row;
            float4 rv = make_float4(0.f, 0.f, 0.f, 0.f);
            if (o >= 0 && o < KLEN) rv = ldg4(&rhk[(size_t)o * (NH*DH) + n*DH + c4]);
            Rs[row][c4+0]=rv.x; Rs[row][c4+1]=rv.y; Rs[row][c4+2]=rv.z; Rs[row][c4+3]=rv.w;
        }
        __syncthreads();

        // phase 1: scores + online softmax. lane = key column.
        const int j = j0 + lane;
        #pragma unroll
        for (int r = 0; r < 16; ++r) {
            const int il = (w << 4) + r;
            const int i = i0 + il;
            float s = NEGF;
            if (j <= i + MLEN) {
                const int ol = lane - il + 63;   // (j-j0)-(i-i0)+63 in [0,126]
                float accs = 0.f;
                #pragma unroll
                for (int d4 = 0; d4 < 16; ++d4) {
                    float4 q  = *reinterpret_cast<const float4*>(&Qw[il][d4 << 2]);
                    float4 k  = *reinterpret_cast<const float4*>(&Ks[lane][d4 << 2]);
                    float4 qr = *reinterpret_cast<const float4*>(&Qr[il][d4 << 2]);
                    float4 rr = *reinterpret_cast<const float4*>(&Rs[ol][d4 << 2]);
                    accs += q.x*k.x + q.y*k.y + q.z*k.z + q.w*k.w
                          + qr.x*rr.x + qr.y*rr.y + qr.z*rr.z + qr.w*rr.w;
                }
                s = accs * 0.125f;
            }
            float mt = s;
            #pragma unroll
            for (int o = 32; o; o >>= 1) mt = fmaxf(mt, __shfl_xor(mt, o));
            float m_new = fmaxf(m_run[r], mt);
            float alpha = __expf(m_run[r] - m_new);
            float p = __expf(s - m_new);
            float ps = p;
            #pragma unroll
            for (int o = 32; o; o >>= 1) ps += __shfl_xor(ps, o);
            l_run[r] = l_run[r] * alpha + ps;
            m_run[r] = m_new;
            Ps[il][lane] = p;
            if (lane == 0) AlphaS[il] = alpha;
        }
        // phase 2: PV accumulate. lane = d. (wave-private rows: no barrier needed)
        #pragma unroll
        for (int r = 0; r < 16; ++r) acc[r] *= AlphaS[(w << 4) + r];
        for (int jl = 0; jl < 64; ++jl) {
            float v = Vs[jl][lane];
            #pragma unroll
            for (int r = 0; r < 16; ++r)
                acc[r] += Ps[(w << 4) + r][jl] * v;
        }
    }

    #pragma unroll
    for (int r = 0; r < 16; ++r) {
        const int il = (w << 4) + r;
        const int i = i0 + il;
        vec[((size_t)(i * BSZ + b)) * DM + n * DH + lane] = acc[r] / l_run[r];
    }
}

// ---------------- Residual + LayerNorm: out = LN(x + res) -------------------
__global__ __launch_bounds__(256) void ln_res_kernel(
    const float* __restrict__ x, const float* __restrict__ res,
    const float* __restrict__ g, const float* __restrict__ bta,
    float* __restrict__ out)
{
    const int row = blockIdx.x;
    const int t = threadIdx.x;
    const int lane = t & 63, wv = t >> 6;
    __shared__ float red0[4], red1[4];

    float4 a = ldg4(&x[(size_t)row * DM + t * 4]);
    float4 b = ldg4(&res[(size_t)row * DM + t * 4]);
    float v0 = a.x + b.x, v1 = a.y + b.y, v2 = a.z + b.z, v3 = a.w + b.w;
    float s = v0 + v1 + v2 + v3;
    #pragma unroll
    for (int o = 32; o; o >>= 1) s += __shfl_xor(s, o);
    if (lane == 0) red0[wv] = s;
    __syncthreads();
    float mu = (red0[0] + red0[1] + red0[2] + red0[3]) * (1.f / DM);
    float d0 = v0 - mu, d1 = v1 - mu, d2 = v2 - mu, d3 = v3 - mu;
    float q = d0*d0 + d1*d1 + d2*d2 + d3*d3;
    #pragma unroll
    for (int o = 32; o; o >>= 1) q += __shfl_xor(q, o);
    if (lane == 0) red1[wv] = q;
    __syncthreads();
    float var = (red1[0] + red1[1] + red1[2] + red1[3]) * (1.f / DM);
    float rs = rsqrtf(var + 1e-5f);
    float4 gv = ldg4(&g[t * 4]);
    float4 bv = ldg4(&bta[t * 4]);
    float4 o4;
    o4.x = d0 * rs * gv.x + bv.x;
    o4.y = d1 * rs * gv.y + bv.y;
    o4.z = d2 * rs * gv.z + bv.z;
    o4.w = d3 * rs * gv.w + bv.w;
    *reinterpret_cast<float4*>(&out[(size_t)row * DM + t * 4]) = o4;
}

// ---------------- launch -----------------------------------------------------
extern "C" void kernel_launch(void* const* d_in, const int* in_sizes, int n_in,
                              void* d_out, int out_size, void* d_ws, size_t ws_size,
                              hipStream_t stream) {
    const float* w     = (const float*)d_in[0];   // [512,8,1024]
    const float* r     = (const float*)d_in[1];   // [1024,1024]
    const float* mems  = (const float*)d_in[2];   // [512,8,1024]
    const float* w_qkv = (const float*)d_in[3];   // [1024,3072]
    const float* w_r   = (const float*)d_in[4];   // [1024,1024]
    const float* w_o   = (const float*)d_in[5];   // [1024,1024]
    const float* rwb   = (const float*)d_in[6];   // [16,64]
    const float* rrb   = (const float*)d_in[7];   // [16,64]
    const float* ln1g  = (const float*)d_in[8];
    const float* ln1b  = (const float*)d_in[9];
    const float* ffw1  = (const float*)d_in[10];  // [1024,4096]
    const float* ffb1  = (const float*)d_in[11];
    const float* ffw2  = (const float*)d_in[12];  // [4096,1024]
    const float* ffb2  = (const float*)d_in[13];
    const float* ln2g  = (const float*)d_in[14];
    const float* ln2b  = (const float*)d_in[15];
    // attn_mask (d_in[16]) recomputed analytically: mask = j > i + MLEN
    (void)in_sizes; (void)n_in; (void)out_size; (void)ws_size;

    float* ws = (float*)d_ws;
    float* heads    = ws;                         // [8192][3072]
    float* rhk      = heads + (size_t)8192*3072;  // [1024][1024]
    float* vec      = rhk + (size_t)1024*1024;    // [4096][1024]
    float* attn_out = vec + (size_t)4096*1024;    // [4096][1024]
    float* h        = attn_out + (size_t)4096*1024; // [4096][1024]
    float* ff1      = h + (size_t)4096*1024;      // [4096][4096]
    float* ff2      = ff1 + (size_t)4096*4096;    // [4096][1024]
    float* outp     = (float*)d_out;

    // 1. heads = concat(mems, w) @ w_qkv    [8192,1024]x[1024,3072]
    gemm64<0, true><<<dim3(48, 128), 256, 0, stream>>>(
        mems, w, 4096, w_qkv, nullptr, heads, 8192, 3072, 1024);
    // 2. r_head_k = r @ w_r                 [1024,1024]x[1024,1024]
    gemm64<0, false><<<dim3(16, 16), 256, 0, stream>>>(
        r, r, 0, w_r, nullptr, rhk, 1024, 1024, 1024);
    // 3. attention -> vec
    attn_kernel<<<dim3(BSZ * NH, QLEN / 64), 256, 0, stream>>>(
        heads, rhk, rwb, rrb, vec);
    // 4. attn_out = vec @ w_o               [4096,1024]x[1024,1024]
    gemm64<0, false><<<dim3(16, 64), 256, 0, stream>>>(
        vec, vec, 0, w_o, nullptr, attn_out, 4096, 1024, 1024);
    // 5. h = LN(w + attn_out)
    ln_res_kernel<<<4096, 256, 0, stream>>>(w, attn_out, ln1g, ln1b, h);
    // 6. ff1 = relu(h @ ff_w1 + b1)         [4096,1024]x[1024,4096]
    gemm64<2, false><<<dim3(64, 64), 256, 0, stream>>>(
        h, h, 0, ffw1, ffb1, ff1, 4096, 4096, 1024);
    // 7. ff2 = ff1 @ ff_w2 + b2             [4096,4096]x[4096,1024]
    gemm64<1, false><<<dim3(16, 64), 256, 0, stream>>>(
        ff1, ff1, 0, ffw2, ffb2, ff2, 4096, 1024, 4096);
    // 8. out = LN(h + ff2)
    ln_res_kernel<<<4096, 256, 0, stream>>>(h, ff2, ln2g, ln2b, outp);
}

// Round 2
// 559.659 us; speedup vs baseline: 6.1810x; 6.1810x over previous
//
#include <hip/hip_runtime.h>
#include <hip/hip_bf16.h>

#define QLEN 512
#define MLEN 512
#define KLEN 1024
#define BSZ 8
#define DM 1024
#define NH 16
#define DH 64
#define DI 4096
#define NEGF (-1e30f)

typedef unsigned short u16;
typedef __attribute__((ext_vector_type(8))) short short8;
typedef __attribute__((ext_vector_type(4))) float f32x4;

__device__ __forceinline__ float bf2f(u16 u) {
    union { unsigned i; float f; } x; x.i = ((unsigned)u) << 16; return x.f;
}
__device__ __forceinline__ u16 f2bf(float f) {
    __hip_bfloat16 h = __float2bfloat16(f);
    return *reinterpret_cast<u16*>(&h);
}
__device__ __forceinline__ float4 ldg4(const float* p) {
    return *reinterpret_cast<const float4*>(p);
}

// ---------------- cast fp32 -> bf16, two-source concat along flat index -----
__global__ __launch_bounds__(256) void cast2_kernel(
    const float* __restrict__ a, const float* __restrict__ b, int splitE,
    u16* __restrict__ out, int n)
{
    int idx = (blockIdx.x * 256 + threadIdx.x) * 4;
    if (idx >= n) return;
    const float* src = (idx < splitE) ? (a + idx) : (b + (idx - splitE));
    float4 v = ldg4(src);
    u16 o[4] = { f2bf(v.x), f2bf(v.y), f2bf(v.z), f2bf(v.w) };
    *reinterpret_cast<uint2*>(&out[idx]) = *reinterpret_cast<uint2*>(o);
}

// ---------------- transpose + cast: W[K][N] fp32 -> WT[N][K] bf16 ------------
__global__ __launch_bounds__(256) void transpose_cast(
    const float* __restrict__ W, u16* __restrict__ WT, int K, int N)
{
    __shared__ float tile[32][33];
    const int k0 = blockIdx.y * 32, n0 = blockIdx.x * 32;
    const int tx = threadIdx.x & 31, ty = threadIdx.x >> 5;
    #pragma unroll
    for (int j = 0; j < 4; ++j)
        tile[ty + j * 8][tx] = W[(size_t)(k0 + ty + j * 8) * N + n0 + tx];
    __syncthreads();
    #pragma unroll
    for (int j = 0; j < 4; ++j)
        WT[(size_t)(n0 + ty + j * 8) * K + k0 + tx] = f2bf(tile[tx][ty + j * 8]);
}

// ---------------- bf16 MFMA GEMM: C[M,N] = A[M,K] @ BT[N,K]^T ----------------
// 128x128 tile, BK=64, 256 threads (4 waves), wave = 64x64 out (4x4 frags of 16x16x32).
template<bool BIAS, bool RELU, bool OUTBF>
__global__ __launch_bounds__(256) void gemm_mfma(
    const u16* __restrict__ A, const u16* __restrict__ BT,
    const float* __restrict__ bias,
    float* __restrict__ Cf, u16* __restrict__ Cb,
    int M, int N, int K)
{
    __shared__ u16 As[128][72];
    __shared__ u16 Bs[128][72];
    const int bm = blockIdx.y * 128, bn = blockIdx.x * 128;
    const int t = threadIdx.x;
    const int w = t >> 6, l = t & 63, lg = l >> 4, lq = l & 15;
    const int wm = (w >> 1) * 64, wn = (w & 1) * 64;
    const int srow = t >> 3, sc = (t & 7) * 8;   // staging coords

    f32x4 acc[4][4];
    #pragma unroll
    for (int x = 0; x < 4; ++x)
        #pragma unroll
        for (int y = 0; y < 4; ++y)
            acc[x][y] = (f32x4){0.f, 0.f, 0.f, 0.f};

    for (int k0 = 0; k0 < K; k0 += 64) {
        __syncthreads();
        #pragma unroll
        for (int rep = 0; rep < 4; ++rep) {
            int r = srow + rep * 32;
            short8 av = *reinterpret_cast<const short8*>(&A[(size_t)(bm + r) * K + k0 + sc]);
            short8 bv = *reinterpret_cast<const short8*>(&BT[(size_t)(bn + r) * K + k0 + sc]);
            *reinterpret_cast<short8*>(&As[r][sc]) = av;
            *reinterpret_cast<short8*>(&Bs[r][sc]) = bv;
        }
        __syncthreads();
        #pragma unroll
        for (int ks = 0; ks < 2; ++ks) {
            short8 af[4], bf_[4];
            #pragma unroll
            for (int x = 0; x < 4; ++x)
                af[x] = *reinterpret_cast<const short8*>(&As[wm + 16 * x + lq][ks * 32 + 8 * lg]);
            #pragma unroll
            for (int y = 0; y < 4; ++y)
                bf_[y] = *reinterpret_cast<const short8*>(&Bs[wn + 16 * y + lq][ks * 32 + 8 * lg]);
            #pragma unroll
            for (int x = 0; x < 4; ++x)
                #pragma unroll
                for (int y = 0; y < 4; ++y)
                    acc[x][y] = __builtin_amdgcn_mfma_f32_16x16x32_bf16(af[x], bf_[y], acc[x][y], 0, 0, 0);
        }
    }
    // epilogue: D[row=4*lg+reg][col=lq] per fragment
    #pragma unroll
    for (int x = 0; x < 4; ++x) {
        #pragma unroll
        for (int y = 0; y < 4; ++y) {
            const int col = bn + wn + 16 * y + lq;
            #pragma unroll
            for (int r = 0; r < 4; ++r) {
                const int row = bm + wm + 16 * x + 4 * lg + r;
                float v = acc[x][y][r];
                if constexpr (BIAS) v += bias[col];
                if constexpr (RELU) v = fmaxf(v, 0.f);
                if constexpr (OUTBF) Cb[(size_t)row * N + col] = f2bf(v);
                else                 Cf[(size_t)row * N + col] = v;
            }
        }
    }
}

// ---------------- MFMA flash relative attention ------------------------------
// Block = (b, head, 64-row q-tile); 4 waves, wave w owns q rows [16w,16w+16).
// S^T = K·Q^T via mfma (D[key][q]); BD via mfma over shifted R window, scattered
// into per-wave score LDS with the rel-shift; softmax fp32 (lane = key);
// PV = P·V via mfma with V staged d-major.
__global__ __launch_bounds__(256) void attn_mfma(
    const u16* __restrict__ heads,   // bf16 [KLEN*BSZ][3*NH*DH]
    const u16* __restrict__ rhk,     // bf16 [KLEN][NH*DH]
    const float* __restrict__ rwb, const float* __restrict__ rrb,
    u16* __restrict__ vec)           // bf16 [QLEN*BSZ][NH*DH]
{
    const int b = blockIdx.x >> 4;
    const int n = blockIdx.x & 15;
    const int i0 = blockIdx.y * 64;
    const int t = threadIdx.x;
    const int w = t >> 6;
    const int l = t & 63;
    const int lg = l >> 4, lq = l & 15;

    __shared__ u16 Ks[64][72];
    __shared__ u16 Vt[64][72];       // d-major: Vt[d][key]
    __shared__ u16 Rs[128][72];
    __shared__ u16 Ps[4][16][72];    // per-wave P[q'][key]
    __shared__ float Sb[4][16][66];  // per-wave scores S[q'][key]
    __shared__ float Al[4][16];
    __shared__ float Ls[4][16];

    // ---- Q fragments (B-operand: lane holds col=q'=lq, k(d)=8*lg+e), persistent
    short8 qw[2], qr[2];
    {
        const int qrow = i0 + 16 * w + lq;
        const size_t gbase = ((size_t)((MLEN + qrow) * BSZ + b)) * 3072 + n * 64;
        #pragma unroll
        for (int ks = 0; ks < 2; ++ks) {
            short8 qv = *reinterpret_cast<const short8*>(&heads[gbase + ks * 32 + 8 * lg]);
            short8 xw, xr;
            #pragma unroll
            for (int e = 0; e < 8; ++e) {
                float f = bf2f((u16)qv[e]);
                int d = ks * 32 + 8 * lg + e;
                xw[e] = (short)f2bf(f + rwb[n * 64 + d]);
                xr[e] = (short)f2bf(f + rrb[n * 64 + d]);
            }
            qw[ks] = xw; qr[ks] = xr;
        }
    }

    float m_run[16], l_run[16];
    #pragma unroll
    for (int r = 0; r < 16; ++r) { m_run[r] = NEGF; l_run[r] = 0.f; }
    f32x4 acc[4];
    #pragma unroll
    for (int df = 0; df < 4; ++df) acc[df] = (f32x4){0.f, 0.f, 0.f, 0.f};

    const int s0 = 48 - 16 * w;                // BD fragment window base
    const int ntiles = (i0 + QLEN + 64) >> 6;

    for (int tile = 0; tile < ntiles; ++tile) {
        const int j0 = tile << 6;
        __syncthreads();
        // ---- stage K (row-major) and V (d-major)
        #pragma unroll
        for (int rep = 0; rep < 2; ++rep) {
            int idx = t + rep * 256;
            int key = idx >> 3, d8 = (idx & 7) * 8;
            size_t gb = ((size_t)((j0 + key) * BSZ + b)) * 3072 + n * 64 + d8;
            short8 kv = *reinterpret_cast<const short8*>(&heads[gb + 1024]);
            short8 vv = *reinterpret_cast<const short8*>(&heads[gb + 2048]);
            *reinterpret_cast<short8*>(&Ks[key][d8]) = kv;
            #pragma unroll
            for (int e = 0; e < 8; ++e) Vt[d8 + e][key] = (u16)vv[e];
        }
        // ---- stage R window rows [obase, obase+128)
        const int obase = j0 - i0 + (QLEN - 1) - 63;
        #pragma unroll
        for (int rep = 0; rep < 4; ++rep) {
            int idx = t + rep * 256;
            int row = idx >> 3, d8 = (idx & 7) * 8;
            int o = obase + row;
            short8 rv = (short8){0,0,0,0,0,0,0,0};
            if (o >= 0 && o < KLEN)
                rv = *reinterpret_cast<const short8*>(&rhk[(size_t)o * 1024 + n * 64 + d8]);
            *reinterpret_cast<short8*>(&Rs[row][d8]) = rv;
        }
        __syncthreads();

        // ---- BD: D[ol][q'] over 5 row-fragments, scatter with rel-shift
        #pragma unroll
        for (int ff = 0; ff < 5; ++ff) {
            f32x4 d = (f32x4){0.f, 0.f, 0.f, 0.f};
            #pragma unroll
            for (int ks = 0; ks < 2; ++ks) {
                short8 a = *reinterpret_cast<const short8*>(&Rs[s0 + 16 * ff + lq][ks * 32 + 8 * lg]);
                d = __builtin_amdgcn_mfma_f32_16x16x32_bf16(a, qr[ks], d, 0, 0, 0);
            }
            #pragma unroll
            for (int r = 0; r < 4; ++r) {
                int ol = s0 + 16 * ff + 4 * lg + r;
                int jl = ol + lq + 16 * w - 63;      // key index in tile
                if (jl >= 0 && jl < 64) Sb[w][lq][jl] = d[r];
            }
        }
        // ---- AC: D[key][q'], accumulate into score buffer
        #pragma unroll
        for (int f = 0; f < 4; ++f) {
            f32x4 d = (f32x4){0.f, 0.f, 0.f, 0.f};
            #pragma unroll
            for (int ks = 0; ks < 2; ++ks) {
                short8 a = *reinterpret_cast<const short8*>(&Ks[16 * f + lq][ks * 32 + 8 * lg]);
                d = __builtin_amdgcn_mfma_f32_16x16x32_bf16(a, qw[ks], d, 0, 0, 0);
            }
            #pragma unroll
            for (int r = 0; r < 4; ++r)
                Sb[w][lq][16 * f + 4 * lg + r] += d[r];
        }

        // ---- softmax (lane = key), fp32, round-1-verified pattern
        const int j = j0 + l;
        #pragma unroll
        for (int r = 0; r < 16; ++r) {
            const int i = i0 + 16 * w + r;
            float s = (j <= i + MLEN) ? Sb[w][r][l] * 0.125f : NEGF;
            float mt = s;
            #pragma unroll
            for (int o = 32; o; o >>= 1) mt = fmaxf(mt, __shfl_xor(mt, o));
            float m_new = fmaxf(m_run[r], mt);
            float alpha = __expf(m_run[r] - m_new);
            float p = __expf(s - m_new);
            float ps = p;
            #pragma unroll
            for (int o = 32; o; o >>= 1) ps += __shfl_xor(ps, o);
            l_run[r] = l_run[r] * alpha + ps;
            m_run[r] = m_new;
            Ps[w][r][l] = f2bf(p);
            if (l == 0) Al[w][r] = alpha;
        }

        // ---- PV: acc[q'][d] = alpha*acc + P@V
        float alr[4];
        #pragma unroll
        for (int r = 0; r < 4; ++r) alr[r] = Al[w][4 * lg + r];
        #pragma unroll
        for (int df = 0; df < 4; ++df) {
            f32x4 a = acc[df];
            #pragma unroll
            for (int r = 0; r < 4; ++r) a[r] *= alr[r];
            #pragma unroll
            for (int ks = 0; ks < 2; ++ks) {
                short8 pa = *reinterpret_cast<const short8*>(&Ps[w][lq][ks * 32 + 8 * lg]);
                short8 vb = *reinterpret_cast<const short8*>(&Vt[16 * df + lq][ks * 32 + 8 * lg]);
                a = __builtin_amdgcn_mfma_f32_16x16x32_bf16(pa, vb, a, 0, 0, 0);
            }
            acc[df] = a;
        }
    }

    // ---- epilogue
    if (l == 0)
        #pragma unroll
        for (int r = 0; r < 16; ++r) Ls[w][r] = l_run[r];
    __builtin_amdgcn_s_waitcnt(0);   // lgkm drain before cross-lane read
    float lsr[4];
    #pragma unroll
    for (int r = 0; r < 4; ++r) lsr[r] = Ls[w][4 * lg + r];
    #pragma unroll
    for (int df = 0; df < 4; ++df) {
        #pragma unroll
        for (int r = 0; r < 4; ++r) {
            const int il = 16 * w + 4 * lg + r;
            float o = acc[df][r] / lsr[r];
            vec[((size_t)((i0 + il) * BSZ + b)) * DM + n * 64 + 16 * df + lq] = f2bf(o);
        }
    }
}

// ---------------- Residual + LayerNorm ---------------------------------------
template<bool WB>
__global__ __launch_bounds__(256) void ln_res_kernel(
    const float* __restrict__ x, const float* __restrict__ res,
    const float* __restrict__ g, const float* __restrict__ bta,
    float* __restrict__ out, u16* __restrict__ outb)
{
    const int row = blockIdx.x;
    const int t = threadIdx.x;
    const int lane = t & 63, wv = t >> 6;
    __shared__ float red0[4], red1[4];

    float4 a = ldg4(&x[(size_t)row * DM + t * 4]);
    float4 b = ldg4(&res[(size_t)row * DM + t * 4]);
    float v0 = a.x + b.x, v1 = a.y + b.y, v2 = a.z + b.z, v3 = a.w + b.w;
    float s = v0 + v1 + v2 + v3;
    #pragma unroll
    for (int o = 32; o; o >>= 1) s += __shfl_xor(s, o);
    if (lane == 0) red0[wv] = s;
    __syncthreads();
    float mu = (red0[0] + red0[1] + red0[2] + red0[3]) * (1.f / DM);
    float d0 = v0 - mu, d1 = v1 - mu, d2 = v2 - mu, d3 = v3 - mu;
    float q = d0*d0 + d1*d1 + d2*d2 + d3*d3;
    #pragma unroll
    for (int o = 32; o; o >>= 1) q += __shfl_xor(q, o);
    if (lane == 0) red1[wv] = q;
    __syncthreads();
    float var = (red1[0] + red1[1] + red1[2] + red1[3]) * (1.f / DM);
    float rs = rsqrtf(var + 1e-5f);
    float4 gv = ldg4(&g[t * 4]);
    float4 bv = ldg4(&bta[t * 4]);
    float o0 = d0 * rs * gv.x + bv.x;
    float o1 = d1 * rs * gv.y + bv.y;
    float o2 = d2 * rs * gv.z + bv.z;
    float o3 = d3 * rs * gv.w + bv.w;
    float4 o4 = make_float4(o0, o1, o2, o3);
    *reinterpret_cast<float4*>(&out[(size_t)row * DM + t * 4]) = o4;
    if constexpr (WB) {
        u16 ob[4] = { f2bf(o0), f2bf(o1), f2bf(o2), f2bf(o3) };
        *reinterpret_cast<uint2*>(&outb[(size_t)row * DM + t * 4]) = *reinterpret_cast<uint2*>(ob);
    }
}

// ---------------- launch ------------------------------------------------------
extern "C" void kernel_launch(void* const* d_in, const int* in_sizes, int n_in,
                              void* d_out, int out_size, void* d_ws, size_t ws_size,
                              hipStream_t stream) {
    const float* w     = (const float*)d_in[0];
    const float* r     = (const float*)d_in[1];
    const float* mems  = (const float*)d_in[2];
    const float* w_qkv = (const float*)d_in[3];
    const float* w_r   = (const float*)d_in[4];
    const float* w_o   = (const float*)d_in[5];
    const float* rwb   = (const float*)d_in[6];
    const float* rrb   = (const float*)d_in[7];
    const float* ln1g  = (const float*)d_in[8];
    const float* ln1b  = (const float*)d_in[9];
    const float* ffw1  = (const float*)d_in[10];
    const float* ffb1  = (const float*)d_in[11];
    const float* ffw2  = (const float*)d_in[12];
    const float* ffb2  = (const float*)d_in[13];
    const float* ln2g  = (const float*)d_in[14];
    const float* ln2b  = (const float*)d_in[15];
    (void)in_sizes; (void)n_in; (void)out_size; (void)ws_size;

    char* p = (char*)d_ws;
    auto alloc = [&](size_t bytes) { char* q = p; p += (bytes + 255) & ~(size_t)255; return q; };
    u16* catB   = (u16*)alloc((size_t)8192 * 1024 * 2);
    u16* rB     = (u16*)alloc((size_t)1024 * 1024 * 2);
    u16* qkvT   = (u16*)alloc((size_t)3072 * 1024 * 2);
    u16* wrT    = (u16*)alloc((size_t)1024 * 1024 * 2);
    u16* woT    = (u16*)alloc((size_t)1024 * 1024 * 2);
    u16* f1T    = (u16*)alloc((size_t)4096 * 1024 * 2);
    u16* f2T    = (u16*)alloc((size_t)1024 * 4096 * 2);
    u16* heads  = (u16*)alloc((size_t)8192 * 3072 * 2);
    u16* rhk    = (u16*)alloc((size_t)1024 * 1024 * 2);
    u16* vec    = (u16*)alloc((size_t)4096 * 1024 * 2);
    u16* hB     = (u16*)alloc((size_t)4096 * 1024 * 2);
    u16* ff1    = (u16*)alloc((size_t)4096 * 4096 * 2);
    float* attn_out = (float*)alloc((size_t)4096 * 1024 * 4);
    float* hF   = (float*)alloc((size_t)4096 * 1024 * 4);
    float* ff2  = (float*)alloc((size_t)4096 * 1024 * 4);
    float* outp = (float*)d_out;

    // casts + weight transposes
    cast2_kernel<<<8192, 256, 0, stream>>>(mems, w, 4096 * 1024, catB, 8192 * 1024);
    cast2_kernel<<<1024, 256, 0, stream>>>(r, r, 1024 * 1024, rB, 1024 * 1024);
    transpose_cast<<<dim3(96, 32), 256, 0, stream>>>(w_qkv, qkvT, 1024, 3072);
    transpose_cast<<<dim3(32, 32), 256, 0, stream>>>(w_r, wrT, 1024, 1024);
    transpose_cast<<<dim3(32, 32), 256, 0, stream>>>(w_o, woT, 1024, 1024);
    transpose_cast<<<dim3(128, 32), 256, 0, stream>>>(ffw1, f1T, 1024, 4096);
    transpose_cast<<<dim3(32, 128), 256, 0, stream>>>(ffw2, f2T, 4096, 1024);

    // 1. heads = cat @ w_qkv
    gemm_mfma<false, false, true><<<dim3(24, 64), 256, 0, stream>>>(
        catB, qkvT, nullptr, nullptr, heads, 8192, 3072, 1024);
    // 2. rhk = r @ w_r
    gemm_mfma<false, false, true><<<dim3(8, 8), 256, 0, stream>>>(
        rB, wrT, nullptr, nullptr, rhk, 1024, 1024, 1024);
    // 3. attention
    attn_mfma<<<dim3(BSZ * NH, QLEN / 64), 256, 0, stream>>>(heads, rhk, rwb, rrb, vec);
    // 4. attn_out = vec @ w_o (fp32 out)
    gemm_mfma<false, false, false><<<dim3(8, 32), 256, 0, stream>>>(
        vec, woT, nullptr, attn_out, nullptr, 4096, 1024, 1024);
    // 5. h = LN(w + attn_out), keep fp32 + bf16
    ln_res_kernel<true><<<4096, 256, 0, stream>>>(w, attn_out, ln1g, ln1b, hF, hB);
    // 6. ff1 = relu(h @ ff_w1 + b1) (bf16 out)
    gemm_mfma<true, true, true><<<dim3(32, 32), 256, 0, stream>>>(
        hB, f1T, ffb1, nullptr, ff1, 4096, 4096, 1024);
    // 7. ff2 = ff1 @ ff_w2 + b2 (fp32 out)
    gemm_mfma<true, false, false><<<dim3(8, 32), 256, 0, stream>>>(
        ff1, f2T, ffb2, ff2, nullptr, 4096, 1024, 4096);
    // 8. out = LN(h + ff2)
    ln_res_kernel<false><<<4096, 256, 0, stream>>>(hF, ff2, ln2g, ln2b, outp, nullptr);
}

// Round 3
// 387.355 us; speedup vs baseline: 8.9304x; 1.4448x over previous
//
#include <hip/hip_runtime.h>
#include <hip/hip_bf16.h>

#define QLEN 512
#define MLEN 512
#define KLEN 1024
#define BSZ 8
#define DM 1024
#define NH 16
#define DH 64
#define DI 4096
#define NEGF (-1e30f)

typedef unsigned short u16;
typedef __attribute__((ext_vector_type(8))) short short8;
typedef __attribute__((ext_vector_type(4))) float f32x4;

__device__ __forceinline__ float bf2f(u16 u) {
    union { unsigned i; float f; } x; x.i = ((unsigned)u) << 16; return x.f;
}
__device__ __forceinline__ u16 f2bf(float f) {
    __hip_bfloat16 h = __float2bfloat16(f);
    return *reinterpret_cast<u16*>(&h);
}
__device__ __forceinline__ float4 ldg4(const float* p) {
    return *reinterpret_cast<const float4*>(p);
}
// async global->LDS DMA, 16B per lane; LDS dest = wave-uniform base + lane*16
__device__ __forceinline__ void gload16(const void* g, void* l) {
    __builtin_amdgcn_global_load_lds(
        (const __attribute__((address_space(1))) void*)g,
        (__attribute__((address_space(3))) void*)l, 16, 0, 0);
}

// ---------------- cast fp32 -> bf16, two-source concat along flat index -----
__global__ __launch_bounds__(256) void cast2_kernel(
    const float* __restrict__ a, const float* __restrict__ b, int splitE,
    u16* __restrict__ out, int n)
{
    int idx = (blockIdx.x * 256 + threadIdx.x) * 4;
    if (idx >= n) return;
    const float* src = (idx < splitE) ? (a + idx) : (b + (idx - splitE));
    float4 v = ldg4(src);
    u16 o[4] = { f2bf(v.x), f2bf(v.y), f2bf(v.z), f2bf(v.w) };
    *reinterpret_cast<uint2*>(&out[idx]) = *reinterpret_cast<uint2*>(o);
}

// ---------------- transpose + cast: W[K][N] fp32 -> WT[N][K] bf16 ------------
__global__ __launch_bounds__(256) void transpose_cast(
    const float* __restrict__ W, u16* __restrict__ WT, int K, int N)
{
    __shared__ float tile[32][33];
    const int k0 = blockIdx.y * 32, n0 = blockIdx.x * 32;
    const int tx = threadIdx.x & 31, ty = threadIdx.x >> 5;
    #pragma unroll
    for (int j = 0; j < 4; ++j)
        tile[ty + j * 8][tx] = W[(size_t)(k0 + ty + j * 8) * N + n0 + tx];
    __syncthreads();
    #pragma unroll
    for (int j = 0; j < 4; ++j)
        WT[(size_t)(n0 + ty + j * 8) * K + k0 + tx] = f2bf(tile[tx][ty + j * 8]);
}

// ---------------- bf16 MFMA GEMM (m97 structure): C = A[M,K] @ BT[N,K]^T -----
// 128x128 tile, BK=64, 4 waves. global_load_lds(16B) staging, linear LDS rows
// (128 B), XOR-swizzled global source + swizzled fragment reads.
template<bool BIAS, bool RELU, bool OUTBF>
__global__ __launch_bounds__(256) void gemm_mfma(
    const u16* __restrict__ A, const u16* __restrict__ BT,
    const float* __restrict__ bias,
    float* __restrict__ Cf, u16* __restrict__ Cb,
    int M, int N, int K)
{
    __shared__ u16 As[128 * 64];
    __shared__ u16 Bs[128 * 64];
    const int bm = blockIdx.y * 128, bn = blockIdx.x * 128;
    const int t = threadIdx.x;
    const int w = t >> 6, l = t & 63, lg = l >> 4, lq = l & 15;
    const int wm = (w >> 1) * 64, wn = (w & 1) * 64;
    const int r8 = l >> 3, slot = l & 7;
    const int gcol = (slot * 16) ^ (r8 << 4);     // swizzled byte col within 128B row

    f32x4 acc[4][4];
    #pragma unroll
    for (int x = 0; x < 4; ++x)
        #pragma unroll
        for (int y = 0; y < 4; ++y)
            acc[x][y] = (f32x4){0.f, 0.f, 0.f, 0.f};

    const int swzr = (lq & 7) << 4;

    for (int k0 = 0; k0 < K; k0 += 64) {
        __syncthreads();
        #pragma unroll
        for (int it = 0; it < 4; ++it) {
            const int base_row = w * 8 + it * 32;          // wave-uniform
            gload16((const char*)A + (((size_t)(bm + base_row + r8) * K + k0) << 1) + gcol,
                    (char*)As + base_row * 128);
            gload16((const char*)BT + (((size_t)(bn + base_row + r8) * K + k0) << 1) + gcol,
                    (char*)Bs + base_row * 128);
        }
        __syncthreads();
        #pragma unroll
        for (int ks = 0; ks < 2; ++ks) {
            const int cb = (ks * 64 + 16 * lg) ^ swzr;
            short8 af[4], bf_[4];
            #pragma unroll
            for (int x = 0; x < 4; ++x)
                af[x] = *reinterpret_cast<const short8*>((char*)As + (wm + 16 * x + lq) * 128 + cb);
            #pragma unroll
            for (int y = 0; y < 4; ++y)
                bf_[y] = *reinterpret_cast<const short8*>((char*)Bs + (wn + 16 * y + lq) * 128 + cb);
            #pragma unroll
            for (int x = 0; x < 4; ++x)
                #pragma unroll
                for (int y = 0; y < 4; ++y)
                    acc[x][y] = __builtin_amdgcn_mfma_f32_16x16x32_bf16(af[x], bf_[y], acc[x][y], 0, 0, 0);
        }
    }
    // epilogue: D[row=4*lg+reg][col=lq] per fragment
    #pragma unroll
    for (int x = 0; x < 4; ++x) {
        #pragma unroll
        for (int y = 0; y < 4; ++y) {
            const int col = bn + wn + 16 * y + lq;
            #pragma unroll
            for (int r = 0; r < 4; ++r) {
                const int row = bm + wm + 16 * x + 4 * lg + r;
                float v = acc[x][y][r];
                if constexpr (BIAS) v += bias[col];
                if constexpr (RELU) v = fmaxf(v, 0.f);
                if constexpr (OUTBF) Cb[(size_t)row * N + col] = f2bf(v);
                else                 Cf[(size_t)row * N + col] = v;
            }
        }
    }
}

// ---------------- MFMA flash relative attention (round-3 redesign) -----------
// Block = (b, head, 64-row q-tile); 4 waves, wave w owns q rows [16w,16w+16).
// AC kept in registers (S^T frags: lane(lg,lq) holds q=lq, keys {16f+4lg+r});
// BD bounced through bf16 LDS with rel-shift scatter; bulk softmax: in-register
// reduce + 2 shuffles; PV via swizzled Ps/Vt. All LDS XOR-swizzled, 48 KB.
__global__ __launch_bounds__(256) void attn_mfma(
    const u16* __restrict__ heads,   // bf16 [KLEN*BSZ][3*NH*DH]
    const u16* __restrict__ rhk,     // bf16 [KLEN][NH*DH]
    const float* __restrict__ rwb, const float* __restrict__ rrb,
    u16* __restrict__ vec)           // bf16 [QLEN*BSZ][NH*DH]
{
    const int b = blockIdx.x >> 4;
    const int n = blockIdx.x & 15;
    const int i0 = (gridDim.y - 1 - blockIdx.y) * 64;   // long blocks first
    const int t = threadIdx.x;
    const int w = t >> 6;
    const int l = t & 63;
    const int lg = l >> 4, lq = l & 15;

    __shared__ u16 Ks[64 * 64];        // 8 KB  [key][d]   swz
    __shared__ u16 Vt[64 * 64];        // 8 KB  [d][key]   swz
    __shared__ u16 Rs[128 * 64];       // 16 KB [o'][d]    swz
    __shared__ u16 Sb[4 * 16 * 64];    // 8 KB  per-wave BD [q'][key] bf16, swz
    __shared__ u16 Ps[4 * 16 * 64];    // 8 KB  per-wave P  [q'][key] bf16, swz

    u16* SbW = Sb + w * 16 * 64;
    u16* PsW = Ps + w * 16 * 64;
    const int swzr = (lq & 7) << 4;    // byte-swizzle for 16B block reads
    const int swzs = (lq & 7) << 3;    // u16-index swizzle for scalar Sb/Ps

    // ---- Q fragments (B-operand: lane holds col=q'=lq, k(d)=32ks+8lg+e)
    short8 qw[2], qr[2];
    {
        const int qrow = i0 + 16 * w + lq;
        const size_t gbase = ((size_t)((MLEN + qrow) * BSZ + b)) * 3072 + n * 64;
        #pragma unroll
        for (int ks = 0; ks < 2; ++ks) {
            short8 qv = *reinterpret_cast<const short8*>(&heads[gbase + ks * 32 + 8 * lg]);
            short8 xw, xr;
            #pragma unroll
            for (int e = 0; e < 8; ++e) {
                float f = bf2f((u16)qv[e]);
                int d = ks * 32 + 8 * lg + e;
                xw[e] = (short)f2bf(f + rwb[n * 64 + d]);
                xr[e] = (short)f2bf(f + rrb[n * 64 + d]);
            }
            qw[ks] = xw; qr[ks] = xr;
        }
    }

    float m_run = NEGF, l_run = 0.f;   // state for q = lq (replicated x4 over lg)
    f32x4 acc[4];
    #pragma unroll
    for (int df = 0; df < 4; ++df) acc[df] = (f32x4){0.f, 0.f, 0.f, 0.f};

    const int s0 = 48 - 16 * w;                // BD fragment window base
    const int ntiles = (i0 + QLEN + 64) >> 6;

    for (int tile = 0; tile < ntiles; ++tile) {
        const int j0 = tile << 6;
        __syncthreads();
        // ---- stage K rows (swizzled global col -> linear LDS)
        #pragma unroll
        for (int rep = 0; rep < 2; ++rep) {
            int idx = t + rep * 256;
            int key = idx >> 3, sl = idx & 7;
            size_t gb = (((size_t)((j0 + key) * BSZ + b)) * 3072 + 1024 + n * 64) * 2;
            int gc = (sl * 16) ^ ((key & 7) << 4);
            short8 kv = *reinterpret_cast<const short8*>((const char*)heads + gb + gc);
            *reinterpret_cast<short8*>((char*)Ks + key * 128 + sl * 16) = kv;
        }
        // ---- stage V transposed: lane = d, coalesced scalar loads, 16B write
        #pragma unroll
        for (int rep = 0; rep < 2; ++rep) {
            int kg = w * 2 + rep;              // key-group of 8
            short8 pv;
            #pragma unroll
            for (int e = 0; e < 8; ++e)
                pv[e] = (short)heads[((size_t)((j0 + kg * 8 + e) * BSZ + b)) * 3072 + 2048 + n * 64 + l];
            *reinterpret_cast<short8*>((char*)Vt + l * 128 + ((kg * 16) ^ ((l & 7) << 4))) = pv;
        }
        // ---- stage R window rows [obase, obase+128)
        const int obase = j0 - i0 + (QLEN - 1) - 63;
        #pragma unroll
        for (int rep = 0; rep < 4; ++rep) {
            int idx = t + rep * 256;
            int row = idx >> 3, sl = idx & 7;
            int o = obase + row;
            short8 rv = (short8){0,0,0,0,0,0,0,0};
            if (o >= 0 && o < KLEN) {
                int gc = (sl * 16) ^ ((row & 7) << 4);
                rv = *reinterpret_cast<const short8*>((const char*)rhk + ((size_t)o * 1024 + n * 64) * 2 + gc);
            }
            *reinterpret_cast<short8*>((char*)Rs + row * 128 + sl * 16) = rv;
        }
        __syncthreads();

        // ---- BD: D[ol][q'=lq] over 5 row-frags; scatter to SbW with rel-shift
        #pragma unroll
        for (int ff = 0; ff < 5; ++ff) {
            f32x4 d = (f32x4){0.f, 0.f, 0.f, 0.f};
            #pragma unroll
            for (int ks = 0; ks < 2; ++ks) {
                short8 a = *reinterpret_cast<const short8*>(
                    (char*)Rs + (s0 + 16 * ff + lq) * 128 + ((ks * 64 + 16 * lg) ^ swzr));
                d = __builtin_amdgcn_mfma_f32_16x16x32_bf16(a, qr[ks], d, 0, 0, 0);
            }
            #pragma unroll
            for (int r = 0; r < 4; ++r) {
                int jl = 16 * ff + 4 * lg + r + lq - 15;   // key index in tile
                if ((unsigned)jl < 64u) SbW[lq * 64 + (jl ^ swzs)] = f2bf(d[r]);
            }
        }
        // ---- AC: D[key][q'=lq], keep in registers
        f32x4 dac[4];
        #pragma unroll
        for (int f = 0; f < 4; ++f) {
            f32x4 d = (f32x4){0.f, 0.f, 0.f, 0.f};
            #pragma unroll
            for (int ks = 0; ks < 2; ++ks) {
                short8 a = *reinterpret_cast<const short8*>(
                    (char*)Ks + (16 * f + lq) * 128 + ((ks * 64 + 16 * lg) ^ swzr));
                d = __builtin_amdgcn_mfma_f32_16x16x32_bf16(a, qw[ks], d, 0, 0, 0);
            }
            dac[f] = d;
        }

        // ---- bulk softmax: lane owns q=lq, keys {16f+4lg+r}; 2+2 shuffles
        const int bound = i0 + 16 * w + lq + MLEN - j0;    // keys k <= bound valid
        float sv[4][4];
        float mx = NEGF;
        #pragma unroll
        for (int f = 0; f < 4; ++f)
            #pragma unroll
            for (int r = 0; r < 4; ++r) {
                int k = 16 * f + 4 * lg + r;
                float bd = bf2f(SbW[lq * 64 + (k ^ swzs)]);
                float x = (k <= bound) ? (dac[f][r] + bd) * 0.125f : NEGF;
                sv[f][r] = x;
                mx = fmaxf(mx, x);
            }
        mx = fmaxf(mx, __shfl_xor(mx, 16));
        mx = fmaxf(mx, __shfl_xor(mx, 32));
        float m_new = fmaxf(m_run, mx);
        float alpha = __expf(m_run - m_new);
        float ps = 0.f;
        #pragma unroll
        for (int f = 0; f < 4; ++f)
            #pragma unroll
            for (int r = 0; r < 4; ++r) {
                int k = 16 * f + 4 * lg + r;
                float p = __expf(sv[f][r] - m_new);
                ps += p;
                PsW[lq * 64 + (k ^ swzs)] = f2bf(p);
            }
        ps += __shfl_xor(ps, 16);
        ps += __shfl_xor(ps, 32);
        l_run = l_run * alpha + ps;
        m_run = m_new;

        // ---- PV: acc[q'][d] = alpha*acc + P@V
        float alr[4];
        #pragma unroll
        for (int r = 0; r < 4; ++r) alr[r] = __shfl(alpha, 20 * lg + r);
        #pragma unroll
        for (int df = 0; df < 4; ++df) {
            f32x4 a = acc[df];
            #pragma unroll
            for (int r = 0; r < 4; ++r) a[r] *= alr[r];
            #pragma unroll
            for (int ks = 0; ks < 2; ++ks) {
                short8 pa = *reinterpret_cast<const short8*>(
                    (char*)PsW + lq * 128 + ((ks * 64 + 16 * lg) ^ swzr));
                short8 vb = *reinterpret_cast<const short8*>(
                    (char*)Vt + (16 * df + lq) * 128 + ((ks * 64 + 16 * lg) ^ swzr));
                a = __builtin_amdgcn_mfma_f32_16x16x32_bf16(pa, vb, a, 0, 0, 0);
            }
            acc[df] = a;
        }
    }

    // ---- epilogue: 1/l via shuffle, D rows q'=4lg+r, col d=16df+lq
    float lsr[4];
    #pragma unroll
    for (int r = 0; r < 4; ++r) lsr[r] = __shfl(l_run, 20 * lg + r);
    #pragma unroll
    for (int df = 0; df < 4; ++df) {
        #pragma unroll
        for (int r = 0; r < 4; ++r) {
            const int il = 16 * w + 4 * lg + r;
            float o = acc[df][r] / lsr[r];
            vec[((size_t)((i0 + il) * BSZ + b)) * DM + n * 64 + 16 * df + lq] = f2bf(o);
        }
    }
}

// ---------------- Residual + LayerNorm ---------------------------------------
template<bool WB>
__global__ __launch_bounds__(256) void ln_res_kernel(
    const float* __restrict__ x, const float* __restrict__ res,
    const float* __restrict__ g, const float* __restrict__ bta,
    float* __restrict__ out, u16* __restrict__ outb)
{
    const int row = blockIdx.x;
    const int t = threadIdx.x;
    const int lane = t & 63, wv = t >> 6;
    __shared__ float red0[4], red1[4];

    float4 a = ldg4(&x[(size_t)row * DM + t * 4]);
    float4 b = ldg4(&res[(size_t)row * DM + t * 4]);
    float v0 = a.x + b.x, v1 = a.y + b.y, v2 = a.z + b.z, v3 = a.w + b.w;
    float s = v0 + v1 + v2 + v3;
    #pragma unroll
    for (int o = 32; o; o >>= 1) s += __shfl_xor(s, o);
    if (lane == 0) red0[wv] = s;
    __syncthreads();
    float mu = (red0[0] + red0[1] + red0[2] + red0[3]) * (1.f / DM);
    float d0 = v0 - mu, d1 = v1 - mu, d2 = v2 - mu, d3 = v3 - mu;
    float q = d0*d0 + d1*d1 + d2*d2 + d3*d3;
    #pragma unroll
    for (int o = 32; o; o >>= 1) q += __shfl_xor(q, o);
    if (lane == 0) red1[wv] = q;
    __syncthreads();
    float var = (red1[0] + red1[1] + red1[2] + red1[3]) * (1.f / DM);
    float rs = rsqrtf(var + 1e-5f);
    float4 gv = ldg4(&g[t * 4]);
    float4 bv = ldg4(&bta[t * 4]);
    float o0 = d0 * rs * gv.x + bv.x;
    float o1 = d1 * rs * gv.y + bv.y;
    float o2 = d2 * rs * gv.z + bv.z;
    float o3 = d3 * rs * gv.w + bv.w;
    float4 o4 = make_float4(o0, o1, o2, o3);
    *reinterpret_cast<float4*>(&out[(size_t)row * DM + t * 4]) = o4;
    if constexpr (WB) {
        u16 ob[4] = { f2bf(o0), f2bf(o1), f2bf(o2), f2bf(o3) };
        *reinterpret_cast<uint2*>(&outb[(size_t)row * DM + t * 4]) = *reinterpret_cast<uint2*>(ob);
    }
}

// ---------------- launch ------------------------------------------------------
extern "C" void kernel_launch(void* const* d_in, const int* in_sizes, int n_in,
                              void* d_out, int out_size, void* d_ws, size_t ws_size,
                              hipStream_t stream) {
    const float* w     = (const float*)d_in[0];
    const float* r     = (const float*)d_in[1];
    const float* mems  = (const float*)d_in[2];
    const float* w_qkv = (const float*)d_in[3];
    const float* w_r   = (const float*)d_in[4];
    const float* w_o   = (const float*)d_in[5];
    const float* rwb   = (const float*)d_in[6];
    const float* rrb   = (const float*)d_in[7];
    const float* ln1g  = (const float*)d_in[8];
    const float* ln1b  = (const float*)d_in[9];
    const float* ffw1  = (const float*)d_in[10];
    const float* ffb1  = (const float*)d_in[11];
    const float* ffw2  = (const float*)d_in[12];
    const float* ffb2  = (const float*)d_in[13];
    const float* ln2g  = (const float*)d_in[14];
    const float* ln2b  = (const float*)d_in[15];
    (void)in_sizes; (void)n_in; (void)out_size; (void)ws_size;

    char* p = (char*)d_ws;
    auto alloc = [&](size_t bytes) { char* q = p; p += (bytes + 255) & ~(size_t)255; return q; };
    u16* catB   = (u16*)alloc((size_t)8192 * 1024 * 2);
    u16* rB     = (u16*)alloc((size_t)1024 * 1024 * 2);
    u16* qkvT   = (u16*)alloc((size_t)3072 * 1024 * 2);
    u16* wrT    = (u16*)alloc((size_t)1024 * 1024 * 2);
    u16* woT    = (u16*)alloc((size_t)1024 * 1024 * 2);
    u16* f1T    = (u16*)alloc((size_t)4096 * 1024 * 2);
    u16* f2T    = (u16*)alloc((size_t)1024 * 4096 * 2);
    u16* heads  = (u16*)alloc((size_t)8192 * 3072 * 2);
    u16* rhk    = (u16*)alloc((size_t)1024 * 1024 * 2);
    u16* vec    = (u16*)alloc((size_t)4096 * 1024 * 2);
    u16* hB     = (u16*)alloc((size_t)4096 * 1024 * 2);
    u16* ff1    = (u16*)alloc((size_t)4096 * 4096 * 2);
    float* attn_out = (float*)alloc((size_t)4096 * 1024 * 4);
    float* hF   = (float*)alloc((size_t)4096 * 1024 * 4);
    float* ff2  = (float*)alloc((size_t)4096 * 1024 * 4);
    float* outp = (float*)d_out;

    // casts + weight transposes
    cast2_kernel<<<8192, 256, 0, stream>>>(mems, w, 4096 * 1024, catB, 8192 * 1024);
    cast2_kernel<<<1024, 256, 0, stream>>>(r, r, 1024 * 1024, rB, 1024 * 1024);
    transpose_cast<<<dim3(96, 32), 256, 0, stream>>>(w_qkv, qkvT, 1024, 3072);
    transpose_cast<<<dim3(32, 32), 256, 0, stream>>>(w_r, wrT, 1024, 1024);
    transpose_cast<<<dim3(32, 32), 256, 0, stream>>>(w_o, woT, 1024, 1024);
    transpose_cast<<<dim3(128, 32), 256, 0, stream>>>(ffw1, f1T, 1024, 4096);
    transpose_cast<<<dim3(32, 128), 256, 0, stream>>>(ffw2, f2T, 4096, 1024);

    // 1. heads = cat @ w_qkv
    gemm_mfma<false, false, true><<<dim3(24, 64), 256, 0, stream>>>(
        catB, qkvT, nullptr, nullptr, heads, 8192, 3072, 1024);
    // 2. rhk = r @ w_r
    gemm_mfma<false, false, true><<<dim3(8, 8), 256, 0, stream>>>(
        rB, wrT, nullptr, nullptr, rhk, 1024, 1024, 1024);
    // 3. attention
    attn_mfma<<<dim3(BSZ * NH, QLEN / 64), 256, 0, stream>>>(heads, rhk, rwb, rrb, vec);
    // 4. attn_out = vec @ w_o (fp32 out)
    gemm_mfma<false, false, false><<<dim3(8, 32), 256, 0, stream>>>(
        vec, woT, nullptr, attn_out, nullptr, 4096, 1024, 1024);
    // 5. h = LN(w + attn_out), keep fp32 + bf16
    ln_res_kernel<true><<<4096, 256, 0, stream>>>(w, attn_out, ln1g, ln1b, hF, hB);
    // 6. ff1 = relu(h @ ff_w1 + b1) (bf16 out)
    gemm_mfma<true, true, true><<<dim3(32, 32), 256, 0, stream>>>(
        hB, f1T, ffb1, nullptr, ff1, 4096, 4096, 1024);
    // 7. ff2 = ff1 @ ff_w2 + b2 (fp32 out)
    gemm_mfma<true, false, false><<<dim3(8, 32), 256, 0, stream>>>(
        ff1, f2T, ffb2, ff2, nullptr, 4096, 1024, 4096);
    // 8. out = LN(h + ff2)
    ln_res_kernel<false><<<4096, 256, 0, stream>>>(hF, ff2, ln2g, ln2b, outp, nullptr);
}

// Round 4
// 377.851 us; speedup vs baseline: 9.1550x; 1.0252x over previous
//
#include <hip/hip_runtime.h>
#include <hip/hip_bf16.h>

#define QLEN 512
#define MLEN 512
#define KLEN 1024
#define BSZ 8
#define DM 1024
#define NH 16
#define DH 64
#define DI 4096
#define NEGF (-1e30f)

typedef unsigned short u16;
typedef __attribute__((ext_vector_type(8))) short short8;
typedef __attribute__((ext_vector_type(4))) short s16x4;
typedef __attribute__((ext_vector_type(4))) float f32x4;

__device__ __forceinline__ float bf2f(u16 u) {
    union { unsigned i; float f; } x; x.i = ((unsigned)u) << 16; return x.f;
}
__device__ __forceinline__ u16 f2bf(float f) {
    __hip_bfloat16 h = __float2bfloat16(f);
    return *reinterpret_cast<u16*>(&h);
}
__device__ __forceinline__ float4 ldg4(const float* p) {
    return *reinterpret_cast<const float4*>(p);
}
// async global->LDS DMA, 16B per lane; LDS dest = wave-uniform base + lane*16
__device__ __forceinline__ void gload16(const void* g, void* l) {
    __builtin_amdgcn_global_load_lds(
        (const __attribute__((address_space(1))) void*)g,
        (__attribute__((address_space(3))) void*)l, 16, 0, 0);
}

// ---------------- cast fp32 -> bf16, two-source concat along flat index -----
__global__ __launch_bounds__(256) void cast2_kernel(
    const float* __restrict__ a, const float* __restrict__ b, int splitE,
    u16* __restrict__ out, int n)
{
    int idx = (blockIdx.x * 256 + threadIdx.x) * 4;
    if (idx >= n) return;
    const float* src = (idx < splitE) ? (a + idx) : (b + (idx - splitE));
    float4 v = ldg4(src);
    u16 o[4] = { f2bf(v.x), f2bf(v.y), f2bf(v.z), f2bf(v.w) };
    *reinterpret_cast<uint2*>(&out[idx]) = *reinterpret_cast<uint2*>(o);
}

// ---------------- transpose + cast: W[K][N] fp32 -> WT[N][K] bf16 ------------
__global__ __launch_bounds__(256) void transpose_cast(
    const float* __restrict__ W, u16* __restrict__ WT, int K, int N)
{
    __shared__ float tile[32][33];
    const int k0 = blockIdx.y * 32, n0 = blockIdx.x * 32;
    const int tx = threadIdx.x & 31, ty = threadIdx.x >> 5;
    #pragma unroll
    for (int j = 0; j < 4; ++j)
        tile[ty + j * 8][tx] = W[(size_t)(k0 + ty + j * 8) * N + n0 + tx];
    __syncthreads();
    #pragma unroll
    for (int j = 0; j < 4; ++j)
        WT[(size_t)(n0 + ty + j * 8) * K + k0 + tx] = f2bf(tile[tx][ty + j * 8]);
}

// ---------------- bf16 MFMA GEMM (m97 structure): C = A[M,K] @ BT[N,K]^T -----
// 128x128 tile, BK=64, 4 waves. global_load_lds(16B) staging, linear LDS rows
// (128 B), XOR-swizzled global source + swizzled fragment reads.
// gridDim.z = split-K: block z covers k range [z*K, (z+1)*K), output buffer z.
template<bool BIAS, bool RELU, bool OUTBF>
__global__ __launch_bounds__(256) void gemm_mfma(
    const u16* __restrict__ A, const u16* __restrict__ BT,
    const float* __restrict__ bias,
    float* __restrict__ Cf, u16* __restrict__ Cb,
    int M, int N, int K, int lda, int ldb)
{
    __shared__ u16 As[128 * 64];
    __shared__ u16 Bs[128 * 64];
    const int bm = blockIdx.y * 128, bn = blockIdx.x * 128;
    const int z = blockIdx.z;
    A  += (size_t)z * K;
    BT += (size_t)z * K;
    const size_t zoff = (size_t)z * M * N;
    const int t = threadIdx.x;
    const int w = t >> 6, l = t & 63, lg = l >> 4, lq = l & 15;
    const int wm = (w >> 1) * 64, wn = (w & 1) * 64;
    const int r8 = l >> 3, slot = l & 7;
    const int gcol = (slot * 16) ^ (r8 << 4);     // swizzled byte col within 128B row

    f32x4 acc[4][4];
    #pragma unroll
    for (int x = 0; x < 4; ++x)
        #pragma unroll
        for (int y = 0; y < 4; ++y)
            acc[x][y] = (f32x4){0.f, 0.f, 0.f, 0.f};

    const int swzr = (lq & 7) << 4;

    for (int k0 = 0; k0 < K; k0 += 64) {
        __syncthreads();
        #pragma unroll
        for (int it = 0; it < 4; ++it) {
            const int base_row = w * 8 + it * 32;          // wave-uniform
            gload16((const char*)A + (((size_t)(bm + base_row + r8) * lda + k0) << 1) + gcol,
                    (char*)As + base_row * 128);
            gload16((const char*)BT + (((size_t)(bn + base_row + r8) * ldb + k0) << 1) + gcol,
                    (char*)Bs + base_row * 128);
        }
        __syncthreads();
        #pragma unroll
        for (int ks = 0; ks < 2; ++ks) {
            const int cb = (ks * 64 + 16 * lg) ^ swzr;
            short8 af[4], bf_[4];
            #pragma unroll
            for (int x = 0; x < 4; ++x)
                af[x] = *reinterpret_cast<const short8*>((char*)As + (wm + 16 * x + lq) * 128 + cb);
            #pragma unroll
            for (int y = 0; y < 4; ++y)
                bf_[y] = *reinterpret_cast<const short8*>((char*)Bs + (wn + 16 * y + lq) * 128 + cb);
            #pragma unroll
            for (int x = 0; x < 4; ++x)
                #pragma unroll
                for (int y = 0; y < 4; ++y)
                    acc[x][y] = __builtin_amdgcn_mfma_f32_16x16x32_bf16(af[x], bf_[y], acc[x][y], 0, 0, 0);
        }
    }
    // epilogue: D[row=4*lg+reg][col=lq] per fragment
    #pragma unroll
    for (int x = 0; x < 4; ++x) {
        #pragma unroll
        for (int y = 0; y < 4; ++y) {
            const int col = bn + wn + 16 * y + lq;
            #pragma unroll
            for (int r = 0; r < 4; ++r) {
                const int row = bm + wm + 16 * x + 4 * lg + r;
                float v = acc[x][y][r];
                if constexpr (BIAS) { if (z == 0) v += bias[col]; }
                if constexpr (RELU) v = fmaxf(v, 0.f);
                if constexpr (OUTBF) Cb[zoff + (size_t)row * N + col] = f2bf(v);
                else                 Cf[zoff + (size_t)row * N + col] = v;
            }
        }
    }
}

// ---------------- MFMA flash relative attention (round-4) --------------------
// Block = (b, head, 64-row q-tile); 4 waves, wave w owns q rows [16w,16w+16).
// AC in registers; BD written ol-indexed (aligned b64, no bounds checks) and
// rel-shifted on the read side; Ps written as packed b64 quads; uniform
// fast-path skips masking on interior tiles.
__global__ __launch_bounds__(256) void attn_mfma(
    const u16* __restrict__ heads,   // bf16 [KLEN*BSZ][3*NH*DH]
    const u16* __restrict__ rhk,     // bf16 [KLEN][NH*DH]
    const float* __restrict__ rwb, const float* __restrict__ rrb,
    u16* __restrict__ vec)           // bf16 [QLEN*BSZ][NH*DH]
{
    const int b = blockIdx.x >> 4;
    const int n = blockIdx.x & 15;
    const int i0 = (gridDim.y - 1 - blockIdx.y) * 64;   // long blocks first
    const int t = threadIdx.x;
    const int w = t >> 6;
    const int l = t & 63;
    const int lg = l >> 4, lq = l & 15;

    __shared__ u16 Ks[64 * 64];        // 8 KB   [key][d]   swz
    __shared__ u16 Vt[64 * 64];        // 8 KB   [d][key]   swz
    __shared__ u16 Rs[128 * 64];       // 16 KB  [o'][d]    swz
    __shared__ u16 SbO[4 * 16 * 84];   // 10.5KB per-wave BD [q'][ol'] bf16
    __shared__ u16 Ps[4 * 16 * 64];    // 8 KB   per-wave P  [q'][key] bf16, swz

    u16* SbW = SbO + w * 16 * 84;
    u16* PsW = Ps + w * 16 * 64;
    const int swzr = (lq & 7) << 4;    // byte-swizzle for 16B block reads

    // ---- Q fragments (B-operand: lane holds col=q'=lq, k(d)=32ks+8lg+e)
    short8 qw[2], qr[2];
    {
        const int qrow = i0 + 16 * w + lq;
        const size_t gbase = ((size_t)((MLEN + qrow) * BSZ + b)) * 3072 + n * 64;
        #pragma unroll
        for (int ks = 0; ks < 2; ++ks) {
            short8 qv = *reinterpret_cast<const short8*>(&heads[gbase + ks * 32 + 8 * lg]);
            short8 xw, xr;
            #pragma unroll
            for (int e = 0; e < 8; ++e) {
                float f = bf2f((u16)qv[e]);
                int d = ks * 32 + 8 * lg + e;
                xw[e] = (short)f2bf(f + rwb[n * 64 + d]);
                xr[e] = (short)f2bf(f + rrb[n * 64 + d]);
            }
            qw[ks] = xw; qr[ks] = xr;
        }
    }

    float m_run = NEGF, l_run = 0.f;   // state for q = lq (replicated x4 over lg)
    f32x4 acc[4];
    #pragma unroll
    for (int df = 0; df < 4; ++df) acc[df] = (f32x4){0.f, 0.f, 0.f, 0.f};

    const int s0 = 48 - 16 * w;                // BD fragment window base
    const int ntiles = (i0 + QLEN + 64) >> 6;

    for (int tile = 0; tile < ntiles; ++tile) {
        const int j0 = tile << 6;
        __syncthreads();
        // ---- stage K rows (swizzled global col -> linear LDS)
        #pragma unroll
        for (int rep = 0; rep < 2; ++rep) {
            int idx = t + rep * 256;
            int key = idx >> 3, sl = idx & 7;
            size_t gb = (((size_t)((j0 + key) * BSZ + b)) * 3072 + 1024 + n * 64) * 2;
            int gc = (sl * 16) ^ ((key & 7) << 4);
            short8 kv = *reinterpret_cast<const short8*>((const char*)heads + gb + gc);
            *reinterpret_cast<short8*>((char*)Ks + key * 128 + sl * 16) = kv;
        }
        // ---- stage V transposed: lane = d, coalesced scalar loads, 16B write
        #pragma unroll
        for (int rep = 0; rep < 2; ++rep) {
            int kg = w * 2 + rep;              // key-group of 8
            short8 pv;
            #pragma unroll
            for (int e = 0; e < 8; ++e)
                pv[e] = (short)heads[((size_t)((j0 + kg * 8 + e) * BSZ + b)) * 3072 + 2048 + n * 64 + l];
            *reinterpret_cast<short8*>((char*)Vt + l * 128 + ((kg * 16) ^ ((l & 7) << 4))) = pv;
        }
        // ---- stage R window rows [obase, obase+128)
        const int obase = j0 - i0 + (QLEN - 1) - 63;
        #pragma unroll
        for (int rep = 0; rep < 4; ++rep) {
            int idx = t + rep * 256;
            int row = idx >> 3, sl = idx & 7;
            int o = obase + row;
            short8 rv = (short8){0,0,0,0,0,0,0,0};
            if (o >= 0 && o < KLEN) {
                int gc = (sl * 16) ^ ((row & 7) << 4);
                rv = *reinterpret_cast<const short8*>((const char*)rhk + ((size_t)o * 1024 + n * 64) * 2 + gc);
            }
            *reinterpret_cast<short8*>((char*)Rs + row * 128 + sl * 16) = rv;
        }
        __syncthreads();

        __builtin_amdgcn_s_setprio(1);
        // ---- BD: D[ol][q'=lq]; write packed b64 quads, ol-indexed (no shift)
        #pragma unroll
        for (int ff = 0; ff < 5; ++ff) {
            f32x4 d = (f32x4){0.f, 0.f, 0.f, 0.f};
            #pragma unroll
            for (int ks = 0; ks < 2; ++ks) {
                short8 a = *reinterpret_cast<const short8*>(
                    (char*)Rs + (s0 + 16 * ff + lq) * 128 + ((ks * 64 + 16 * lg) ^ swzr));
                d = __builtin_amdgcn_mfma_f32_16x16x32_bf16(a, qr[ks], d, 0, 0, 0);
            }
            s16x4 pk;
            #pragma unroll
            for (int r = 0; r < 4; ++r) pk[r] = (short)f2bf(d[r]);
            *reinterpret_cast<s16x4*>(&SbW[lq * 84 + 16 * ff + 4 * lg]) = pk;
        }
        // ---- AC: D[key][q'=lq], keep in registers
        f32x4 dac[4];
        #pragma unroll
        for (int f = 0; f < 4; ++f) {
            f32x4 d = (f32x4){0.f, 0.f, 0.f, 0.f};
            #pragma unroll
            for (int ks = 0; ks < 2; ++ks) {
                short8 a = *reinterpret_cast<const short8*>(
                    (char*)Ks + (16 * f + lq) * 128 + ((ks * 64 + 16 * lg) ^ swzr));
                d = __builtin_amdgcn_mfma_f32_16x16x32_bf16(a, qw[ks], d, 0, 0, 0);
            }
            dac[f] = d;
        }
        __builtin_amdgcn_s_setprio(0);

        // ---- bulk softmax: lane owns q=lq, keys {16f+4lg+r}; rel-shift on read
        const bool fullTile = (i0 + 16 * w + MLEN - j0) >= 63;  // wave-uniform
        float sv[4][4];
        float mx = NEGF;
        if (fullTile) {
            #pragma unroll
            for (int f = 0; f < 4; ++f)
                #pragma unroll
                for (int r = 0; r < 4; ++r) {
                    int k = 16 * f + 4 * lg + r;
                    float bd = bf2f(SbW[lq * 84 + k - lq + 15]);
                    float x = (dac[f][r] + bd) * 0.125f;
                    sv[f][r] = x;
                    mx = fmaxf(mx, x);
                }
        } else {
            const int bound = i0 + 16 * w + lq + MLEN - j0;     // keys k <= bound
            #pragma unroll
            for (int f = 0; f < 4; ++f)
                #pragma unroll
                for (int r = 0; r < 4; ++r) {
                    int k = 16 * f + 4 * lg + r;
                    float bd = bf2f(SbW[lq * 84 + k - lq + 15]);
                    float x = (k <= bound) ? (dac[f][r] + bd) * 0.125f : NEGF;
                    sv[f][r] = x;
                    mx = fmaxf(mx, x);
                }
        }
        mx = fmaxf(mx, __shfl_xor(mx, 16));
        mx = fmaxf(mx, __shfl_xor(mx, 32));
        float m_new = fmaxf(m_run, mx);
        float alpha = __expf(m_run - m_new);
        float ps = 0.f;
        #pragma unroll
        for (int f = 0; f < 4; ++f) {
            s16x4 pk;
            #pragma unroll
            for (int r = 0; r < 4; ++r) {
                float p = __expf(sv[f][r] - m_new);
                ps += p;
                pk[r] = (short)f2bf(p);
            }
            // key-block kb = 4f+lg, swizzled kb' = kb ^ ((lq&7)<<1), 8B store
            *reinterpret_cast<s16x4*>(
                (char*)PsW + lq * 128 + (((4 * f + lg) ^ ((lq & 7) << 1)) << 3)) = pk;
        }
        ps += __shfl_xor(ps, 16);
        ps += __shfl_xor(ps, 32);
        l_run = l_run * alpha + ps;
        m_run = m_new;

        // ---- PV: acc[q'][d] = alpha*acc + P@V
        float alr[4];
        #pragma unroll
        for (int r = 0; r < 4; ++r) alr[r] = __shfl(alpha, 20 * lg + r);
        __builtin_amdgcn_s_setprio(1);
        #pragma unroll
        for (int df = 0; df < 4; ++df) {
            f32x4 a = acc[df];
            #pragma unroll
            for (int r = 0; r < 4; ++r) a[r] *= alr[r];
            #pragma unroll
            for (int ks = 0; ks < 2; ++ks) {
                short8 pa = *reinterpret_cast<const short8*>(
                    (char*)PsW + lq * 128 + ((ks * 64 + 16 * lg) ^ swzr));
                short8 vb = *reinterpret_cast<const short8*>(
                    (char*)Vt + (16 * df + lq) * 128 + ((ks * 64 + 16 * lg) ^ swzr));
                a = __builtin_amdgcn_mfma_f32_16x16x32_bf16(pa, vb, a, 0, 0, 0);
            }
            acc[df] = a;
        }
        __builtin_amdgcn_s_setprio(0);
    }

    // ---- epilogue: 1/l via shuffle, D rows q'=4lg+r, col d=16df+lq
    float inv[4];
    #pragma unroll
    for (int r = 0; r < 4; ++r) inv[r] = 1.f / __shfl(l_run, 20 * lg + r);
    #pragma unroll
    for (int df = 0; df < 4; ++df) {
        #pragma unroll
        for (int r = 0; r < 4; ++r) {
            const int il = 16 * w + 4 * lg + r;
            float o = acc[df][r] * inv[r];
            vec[((size_t)((i0 + il) * BSZ + b)) * DM + n * 64 + 16 * df + lq] = f2bf(o);
        }
    }
}

// ---------------- Residual + LayerNorm (1 or 2 residual streams) -------------
template<int NRES, bool WB>
__global__ __launch_bounds__(256) void ln_res_kernel(
    const float* __restrict__ x, const float* __restrict__ res,
    const float* __restrict__ res2,
    const float* __restrict__ g, const float* __restrict__ bta,
    float* __restrict__ out, u16* __restrict__ outb)
{
    const int row = blockIdx.x;
    const int t = threadIdx.x;
    const int lane = t & 63, wv = t >> 6;
    __shared__ float red0[4], red1[4];

    float4 a = ldg4(&x[(size_t)row * DM + t * 4]);
    float4 b = ldg4(&res[(size_t)row * DM + t * 4]);
    float v0 = a.x + b.x, v1 = a.y + b.y, v2 = a.z + b.z, v3 = a.w + b.w;
    if constexpr (NRES == 2) {
        float4 c = ldg4(&res2[(size_t)row * DM + t * 4]);
        v0 += c.x; v1 += c.y; v2 += c.z; v3 += c.w;
    }
    float s = v0 + v1 + v2 + v3;
    #pragma unroll
    for (int o = 32; o; o >>= 1) s += __shfl_xor(s, o);
    if (lane == 0) red0[wv] = s;
    __syncthreads();
    float mu = (red0[0] + red0[1] + red0[2] + red0[3]) * (1.f / DM);
    float d0 = v0 - mu, d1 = v1 - mu, d2 = v2 - mu, d3 = v3 - mu;
    float q = d0*d0 + d1*d1 + d2*d2 + d3*d3;
    #pragma unroll
    for (int o = 32; o; o >>= 1) q += __shfl_xor(q, o);
    if (lane == 0) red1[wv] = q;
    __syncthreads();
    float var = (red1[0] + red1[1] + red1[2] + red1[3]) * (1.f / DM);
    float rs = rsqrtf(var + 1e-5f);
    float4 gv = ldg4(&g[t * 4]);
    float4 bv = ldg4(&bta[t * 4]);
    float o0 = d0 * rs * gv.x + bv.x;
    float o1 = d1 * rs * gv.y + bv.y;
    float o2 = d2 * rs * gv.z + bv.z;
    float o3 = d3 * rs * gv.w + bv.w;
    float4 o4 = make_float4(o0, o1, o2, o3);
    *reinterpret_cast<float4*>(&out[(size_t)row * DM + t * 4]) = o4;
    if constexpr (WB) {
        u16 ob[4] = { f2bf(o0), f2bf(o1), f2bf(o2), f2bf(o3) };
        *reinterpret_cast<uint2*>(&outb[(size_t)row * DM + t * 4]) = *reinterpret_cast<uint2*>(ob);
    }
}

// ---------------- launch ------------------------------------------------------
extern "C" void kernel_launch(void* const* d_in, const int* in_sizes, int n_in,
                              void* d_out, int out_size, void* d_ws, size_t ws_size,
                              hipStream_t stream) {
    const float* w     = (const float*)d_in[0];
    const float* r     = (const float*)d_in[1];
    const float* mems  = (const float*)d_in[2];
    const float* w_qkv = (const float*)d_in[3];
    const float* w_r   = (const float*)d_in[4];
    const float* w_o   = (const float*)d_in[5];
    const float* rwb   = (const float*)d_in[6];
    const float* rrb   = (const float*)d_in[7];
    const float* ln1g  = (const float*)d_in[8];
    const float* ln1b  = (const float*)d_in[9];
    const float* ffw1  = (const float*)d_in[10];
    const float* ffb1  = (const float*)d_in[11];
    const float* ffw2  = (const float*)d_in[12];
    const float* ffb2  = (const float*)d_in[13];
    const float* ln2g  = (const float*)d_in[14];
    const float* ln2b  = (const float*)d_in[15];
    (void)in_sizes; (void)n_in; (void)out_size; (void)ws_size;

    char* p = (char*)d_ws;
    auto alloc = [&](size_t bytes) { char* q = p; p += (bytes + 255) & ~(size_t)255; return q; };
    u16* catB   = (u16*)alloc((size_t)8192 * 1024 * 2);
    u16* rB     = (u16*)alloc((size_t)1024 * 1024 * 2);
    u16* qkvT   = (u16*)alloc((size_t)3072 * 1024 * 2);
    u16* wrT    = (u16*)alloc((size_t)1024 * 1024 * 2);
    u16* woT    = (u16*)alloc((size_t)1024 * 1024 * 2);
    u16* f1T    = (u16*)alloc((size_t)4096 * 1024 * 2);
    u16* f2T    = (u16*)alloc((size_t)1024 * 4096 * 2);
    u16* heads  = (u16*)alloc((size_t)8192 * 3072 * 2);
    u16* rhk    = (u16*)alloc((size_t)1024 * 1024 * 2);
    u16* vec    = (u16*)alloc((size_t)4096 * 1024 * 2);
    u16* hB     = (u16*)alloc((size_t)4096 * 1024 * 2);
    u16* ff1    = (u16*)alloc((size_t)4096 * 4096 * 2);
    float* attn_out = (float*)alloc((size_t)4096 * 1024 * 4);
    float* hF   = (float*)alloc((size_t)4096 * 1024 * 4);
    float* ff2  = (float*)alloc((size_t)2 * 4096 * 1024 * 4);   // split-K x2
    float* outp = (float*)d_out;

    // casts + weight transposes
    cast2_kernel<<<8192, 256, 0, stream>>>(mems, w, 4096 * 1024, catB, 8192 * 1024);
    cast2_kernel<<<1024, 256, 0, stream>>>(r, r, 1024 * 1024, rB, 1024 * 1024);
    transpose_cast<<<dim3(96, 32), 256, 0, stream>>>(w_qkv, qkvT, 1024, 3072);
    transpose_cast<<<dim3(32, 32), 256, 0, stream>>>(w_r, wrT, 1024, 1024);
    transpose_cast<<<dim3(32, 32), 256, 0, stream>>>(w_o, woT, 1024, 1024);
    transpose_cast<<<dim3(128, 32), 256, 0, stream>>>(ffw1, f1T, 1024, 4096);
    transpose_cast<<<dim3(32, 128), 256, 0, stream>>>(ffw2, f2T, 4096, 1024);

    // 1. heads = cat @ w_qkv
    gemm_mfma<false, false, true><<<dim3(24, 64), 256, 0, stream>>>(
        catB, qkvT, nullptr, nullptr, heads, 8192, 3072, 1024, 1024, 1024);
    // 2. rhk = r @ w_r
    gemm_mfma<false, false, true><<<dim3(8, 8), 256, 0, stream>>>(
        rB, wrT, nullptr, nullptr, rhk, 1024, 1024, 1024, 1024, 1024);
    // 3. attention
    attn_mfma<<<dim3(BSZ * NH, QLEN / 64), 256, 0, stream>>>(heads, rhk, rwb, rrb, vec);
    // 4. attn_out = vec @ w_o (fp32 out)
    gemm_mfma<false, false, false><<<dim3(8, 32), 256, 0, stream>>>(
        vec, woT, nullptr, attn_out, nullptr, 4096, 1024, 1024, 1024, 1024);
    // 5. h = LN(w + attn_out), keep fp32 + bf16
    ln_res_kernel<1, true><<<4096, 256, 0, stream>>>(w, attn_out, nullptr, ln1g, ln1b, hF, hB);
    // 6. ff1 = relu(h @ ff_w1 + b1) (bf16 out)
    gemm_mfma<true, true, true><<<dim3(32, 32), 256, 0, stream>>>(
        hB, f1T, ffb1, nullptr, ff1, 4096, 4096, 1024, 1024, 1024);
    // 7. ff2 = ff1 @ ff_w2 + b2, split-K x2 via gridDim.z (fp32 partials)
    gemm_mfma<true, false, false><<<dim3(8, 32, 2), 256, 0, stream>>>(
        ff1, f2T, ffb2, ff2, nullptr, 4096, 1024, 2048, 4096, 4096);
    // 8. out = LN(h + ff2a + ff2b)
    ln_res_kernel<2, false><<<4096, 256, 0, stream>>>(
        hF, ff2, ff2 + (size_t)4096 * 1024, ln2g, ln2b, outp, nullptr);
}

// Round 5
// 344.463 us; speedup vs baseline: 10.0424x; 1.0969x over previous
//
#include <hip/hip_runtime.h>
#include <hip/hip_bf16.h>

#define QLEN 512
#define MLEN 512
#define KLEN 1024
#define BSZ 8
#define DM 1024
#define NH 16
#define DH 64
#define DI 4096
#define NEGF (-1e30f)

typedef unsigned short u16;
typedef __attribute__((ext_vector_type(8))) short short8;
typedef __attribute__((ext_vector_type(4))) short s16x4;
typedef __attribute__((ext_vector_type(4))) float f32x4;

__device__ __forceinline__ float bf2f(u16 u) {
    union { unsigned i; float f; } x; x.i = ((unsigned)u) << 16; return x.f;
}
__device__ __forceinline__ u16 f2bf(float f) {
    __hip_bfloat16 h = __float2bfloat16(f);
    return *reinterpret_cast<u16*>(&h);
}
__device__ __forceinline__ float4 ldg4(const float* p) {
    return *reinterpret_cast<const float4*>(p);
}
// async global->LDS DMA, 16B per lane; LDS dest = wave-uniform base + lane*16
__device__ __forceinline__ void gload16(const void* g, void* l) {
    __builtin_amdgcn_global_load_lds(
        (const __attribute__((address_space(1))) void*)g,
        (__attribute__((address_space(3))) void*)l, 16, 0, 0);
}

// ---------------- cast fp32 -> bf16, two-source concat along flat index -----
__global__ __launch_bounds__(256) void cast2_kernel(
    const float* __restrict__ a, const float* __restrict__ b, int splitE,
    u16* __restrict__ out, int n)
{
    int idx = (blockIdx.x * 256 + threadIdx.x) * 4;
    if (idx >= n) return;
    const float* src = (idx < splitE) ? (a + idx) : (b + (idx - splitE));
    float4 v = ldg4(src);
    u16 o[4] = { f2bf(v.x), f2bf(v.y), f2bf(v.z), f2bf(v.w) };
    *reinterpret_cast<uint2*>(&out[idx]) = *reinterpret_cast<uint2*>(o);
}

// ---------------- fused weight transposes: 5 matrices in one launch ----------
__device__ __forceinline__ void tr32(
    const float* __restrict__ W, u16* __restrict__ WT, int K, int N, int k0, int n0)
{
    __shared__ float tile[32][33];
    const int tx = threadIdx.x & 31, ty = threadIdx.x >> 5;
    #pragma unroll
    for (int j = 0; j < 4; ++j)
        tile[ty + j * 8][tx] = W[(size_t)(k0 + ty + j * 8) * N + n0 + tx];
    __syncthreads();
    #pragma unroll
    for (int j = 0; j < 4; ++j)
        WT[(size_t)(n0 + ty + j * 8) * K + k0 + tx] = f2bf(tile[tx][ty + j * 8]);
}

__global__ __launch_bounds__(256) void transpose_all(
    const float* __restrict__ w_qkv, u16* __restrict__ qkvT,
    const float* __restrict__ w_r,   u16* __restrict__ wrT,
    const float* __restrict__ w_o,   u16* __restrict__ woT,
    const float* __restrict__ ffw1,  u16* __restrict__ f1T,
    const float* __restrict__ ffw2,  u16* __restrict__ f2T)
{
    int id = blockIdx.x;
    if (id < 3072)       { int l = id;        tr32(w_qkv, qkvT, 1024, 3072, (l / 96) * 32, (l % 96) * 32); }
    else if (id < 4096)  { int l = id - 3072; tr32(w_r,   wrT,  1024, 1024, (l / 32) * 32, (l % 32) * 32); }
    else if (id < 5120)  { int l = id - 4096; tr32(w_o,   woT,  1024, 1024, (l / 32) * 32, (l % 32) * 32); }
    else if (id < 9216)  { int l = id - 5120; tr32(ffw1,  f1T,  1024, 4096, (l / 128) * 32, (l % 128) * 32); }
    else                 { int l = id - 9216; tr32(ffw2,  f2T,  4096, 1024, (l / 32) * 32, (l % 32) * 32); }
}

// ---------------- V transpose: heads V-part -> Vg[(b,h)][d][key] bf16 --------
__global__ __launch_bounds__(256) void v_transpose(
    const u16* __restrict__ heads, u16* __restrict__ Vg)
{
    const int bn = blockIdx.x;            // b*16+n
    const int b = bn >> 4, n = bn & 15;
    const int kt = blockIdx.y;            // 64-key tile
    const int t = threadIdx.x;
    __shared__ u16 L[64 * 64];            // [key][d], col-swizzled

    #pragma unroll
    for (int rep = 0; rep < 2; ++rep) {
        int idx = t + rep * 256;
        int key = idx >> 3, dc = (idx & 7) * 8;
        short8 v = *reinterpret_cast<const short8*>(
            &heads[((size_t)((kt * 64 + key) * BSZ + b)) * 3072 + 2048 + n * 64 + dc]);
        *reinterpret_cast<short8*>((char*)L + key * 128 + ((dc * 2) ^ ((key & 7) << 4))) = v;
    }
    __syncthreads();
    #pragma unroll
    for (int rep = 0; rep < 2; ++rep) {
        int idx = t + rep * 256;
        int d = idx >> 3, kc = (idx & 7) * 8;
        short8 o;
        #pragma unroll
        for (int e = 0; e < 8; ++e)
            o[e] = *(const short*)((char*)L + (kc + e) * 128 + ((d * 2) ^ (((kc + e) & 7) << 4)));
        *reinterpret_cast<short8*>(&Vg[((size_t)(bn * 64 + d)) * KLEN + kt * 64 + kc]) = o;
    }
}

// ---------------- bf16 MFMA GEMM (m97 structure): C = A[M,K] @ BT[N,K]^T -----
// 128x128 tile, BK=64, 4 waves. global_load_lds(16B) staging, linear LDS rows
// (128 B), XOR-swizzled global source + swizzled fragment reads.
// gridDim.z = split-K: block z covers k range [z*K, (z+1)*K), output buffer z.
template<bool BIAS, bool RELU, bool OUTBF>
__global__ __launch_bounds__(256) void gemm_mfma(
    const u16* __restrict__ A, const u16* __restrict__ BT,
    const float* __restrict__ bias,
    float* __restrict__ Cf, u16* __restrict__ Cb,
    int M, int N, int K, int lda, int ldb)
{
    __shared__ u16 As[128 * 64];
    __shared__ u16 Bs[128 * 64];
    const int bm = blockIdx.y * 128, bn = blockIdx.x * 128;
    const int z = blockIdx.z;
    A  += (size_t)z * K;
    BT += (size_t)z * K;
    const size_t zoff = (size_t)z * M * N;
    const int t = threadIdx.x;
    const int w = t >> 6, l = t & 63, lg = l >> 4, lq = l & 15;
    const int wm = (w >> 1) * 64, wn = (w & 1) * 64;
    const int r8 = l >> 3, slot = l & 7;
    const int gcol = (slot * 16) ^ (r8 << 4);     // swizzled byte col within 128B row

    f32x4 acc[4][4];
    #pragma unroll
    for (int x = 0; x < 4; ++x)
        #pragma unroll
        for (int y = 0; y < 4; ++y)
            acc[x][y] = (f32x4){0.f, 0.f, 0.f, 0.f};

    const int swzr = (lq & 7) << 4;

    for (int k0 = 0; k0 < K; k0 += 64) {
        __syncthreads();
        #pragma unroll
        for (int it = 0; it < 4; ++it) {
            const int base_row = w * 8 + it * 32;          // wave-uniform
            gload16((const char*)A + (((size_t)(bm + base_row + r8) * lda + k0) << 1) + gcol,
                    (char*)As + base_row * 128);
            gload16((const char*)BT + (((size_t)(bn + base_row + r8) * ldb + k0) << 1) + gcol,
                    (char*)Bs + base_row * 128);
        }
        __syncthreads();
        #pragma unroll
        for (int ks = 0; ks < 2; ++ks) {
            const int cb = (ks * 64 + 16 * lg) ^ swzr;
            short8 af[4], bf_[4];
            #pragma unroll
            for (int x = 0; x < 4; ++x)
                af[x] = *reinterpret_cast<const short8*>((char*)As + (wm + 16 * x + lq) * 128 + cb);
            #pragma unroll
            for (int y = 0; y < 4; ++y)
                bf_[y] = *reinterpret_cast<const short8*>((char*)Bs + (wn + 16 * y + lq) * 128 + cb);
            #pragma unroll
            for (int x = 0; x < 4; ++x)
                #pragma unroll
                for (int y = 0; y < 4; ++y)
                    acc[x][y] = __builtin_amdgcn_mfma_f32_16x16x32_bf16(af[x], bf_[y], acc[x][y], 0, 0, 0);
        }
    }
    // epilogue: D[row=4*lg+reg][col=lq] per fragment
    #pragma unroll
    for (int x = 0; x < 4; ++x) {
        #pragma unroll
        for (int y = 0; y < 4; ++y) {
            const int col = bn + wn + 16 * y + lq;
            #pragma unroll
            for (int r = 0; r < 4; ++r) {
                const int row = bm + wm + 16 * x + 4 * lg + r;
                float v = acc[x][y][r];
                if constexpr (BIAS) { if (z == 0) v += bias[col]; }
                if constexpr (RELU) v = fmaxf(v, 0.f);
                if constexpr (OUTBF) Cb[zoff + (size_t)row * N + col] = f2bf(v);
                else                 Cf[zoff + (size_t)row * N + col] = v;
            }
        }
    }
}

// ---------------- MFMA flash relative attention (round-5) --------------------
// Block = (b, head, 128-row q-tile); 8 waves (512 thr), wave w owns q rows
// [16w,16w+16). K/V/R staged via global_load_lds(16B) with pre-swizzled global
// source; V comes pre-transposed (Vg). R rows clamped to KLEN-1 (clamped rows
// only feed masked or never-read score entries). AC in registers; BD bounced
// ol-indexed through LDS; bulk in-register softmax (2+2 shuffles).
__global__ __launch_bounds__(512, 4) void attn_mfma(
    const u16* __restrict__ heads,   // bf16 [KLEN*BSZ][3*NH*DH]
    const u16* __restrict__ Vg,      // bf16 [(b,h)][DH][KLEN]
    const u16* __restrict__ rhk,     // bf16 [KLEN][NH*DH]
    const float* __restrict__ rwb, const float* __restrict__ rrb,
    u16* __restrict__ vec)           // bf16 [QLEN*BSZ][NH*DH]
{
    const int b = blockIdx.x >> 4;
    const int n = blockIdx.x & 15;
    const int i0 = (3 - blockIdx.y) * 128;      // long blocks first
    const int t = threadIdx.x;
    const int w = t >> 6;                        // 0..7
    const int l = t & 63;
    const int lg = l >> 4, lq = l & 15;
    const int r8 = l >> 3, sl = l & 7;

    __shared__ u16 Ks[64 * 64];        // 8 KB   [key][d]
    __shared__ u16 Vt[64 * 64];        // 8 KB   [d][key]
    __shared__ u16 Rs[192 * 64];       // 24 KB  [ol][d]
    __shared__ u16 SbO[8 * 16 * 84];   // 21 KB  per-wave BD [q'][ol'] bf16
    __shared__ u16 Ps[8 * 16 * 64];    // 16 KB  per-wave P  [q'][key] bf16, swz

    u16* SbW = SbO + w * 16 * 84;
    u16* PsW = Ps + w * 16 * 64;
    const int swzr = (lq & 7) << 4;    // byte-swizzle for 16B block reads
    const int stg_swz = (sl * 16) ^ (r8 << 4);  // staging source col swizzle

    // ---- Q fragments (B-operand: lane holds col=q'=lq, k(d)=32ks+8lg+e)
    short8 qw[2], qr[2];
    {
        const int qrow = i0 + 16 * w + lq;
        const size_t gbase = ((size_t)((MLEN + qrow) * BSZ + b)) * 3072 + n * 64;
        #pragma unroll
        for (int ks = 0; ks < 2; ++ks) {
            short8 qv = *reinterpret_cast<const short8*>(&heads[gbase + ks * 32 + 8 * lg]);
            short8 xw, xr;
            #pragma unroll
            for (int e = 0; e < 8; ++e) {
                float f = bf2f((u16)qv[e]);
                int d = ks * 32 + 8 * lg + e;
                xw[e] = (short)f2bf(f + rwb[n * 64 + d]);
                xr[e] = (short)f2bf(f + rrb[n * 64 + d]);
            }
            qw[ks] = xw; qr[ks] = xr;
        }
    }

    float m_run = NEGF, l_run = 0.f;   // state for q = lq (replicated x4 over lg)
    f32x4 acc[4];
    #pragma unroll
    for (int df = 0; df < 4; ++df) acc[df] = (f32x4){0.f, 0.f, 0.f, 0.f};

    const int s0 = 112 - 16 * w;               // BD fragment window base
    const int ntiles = i0 / 64 + 10;

    for (int tile = 0; tile < ntiles; ++tile) {
        const int j0 = tile << 6;
        __syncthreads();   // previous tile fully consumed
        // ---- K: 64 rows x 128B, one pass (512 lanes x 16B)
        gload16((const char*)heads
                    + (((size_t)((j0 + w * 8 + r8) * BSZ + b)) * 3072 + 1024 + n * 64) * 2
                    + stg_swz,
                (char*)Ks + w * 1024);
        // ---- V (pre-transposed): row d = w*8+r8
        gload16((const char*)Vg
                    + (((size_t)(blockIdx.x * 64 + w * 8 + r8)) * KLEN + j0) * 2
                    + stg_swz,
                (char*)Vt + w * 1024);
        // ---- R: 192 rows, 3 passes; clamp row index (safe: see header comment)
        const int obase = j0 - i0 + 384;
        #pragma unroll
        for (int pass = 0; pass < 3; ++pass) {
            int row = pass * 64 + w * 8 + r8;
            int o = obase + row;
            o = o > (KLEN - 1) ? (KLEN - 1) : o;
            gload16((const char*)rhk + ((size_t)o * 1024 + n * 64) * 2 + stg_swz,
                    (char*)Rs + pass * 8192 + w * 1024);
        }
        __syncthreads();

        __builtin_amdgcn_s_setprio(1);
        // ---- BD: D[ol][q'=lq]; write packed b64 quads, ol-indexed
        #pragma unroll
        for (int ff = 0; ff < 5; ++ff) {
            f32x4 d = (f32x4){0.f, 0.f, 0.f, 0.f};
            #pragma unroll
            for (int ks = 0; ks < 2; ++ks) {
                short8 a = *reinterpret_cast<const short8*>(
                    (char*)Rs + (s0 + 16 * ff + lq) * 128 + ((ks * 64 + 16 * lg) ^ swzr));
                d = __builtin_amdgcn_mfma_f32_16x16x32_bf16(a, qr[ks], d, 0, 0, 0);
            }
            s16x4 pk;
            #pragma unroll
            for (int r = 0; r < 4; ++r) pk[r] = (short)f2bf(d[r]);
            *reinterpret_cast<s16x4*>(&SbW[lq * 84 + 16 * ff + 4 * lg]) = pk;
        }
        // ---- AC: D[key][q'=lq], keep in registers
        f32x4 dac[4];
        #pragma unroll
        for (int f = 0; f < 4; ++f) {
            f32x4 d = (f32x4){0.f, 0.f, 0.f, 0.f};
            #pragma unroll
            for (int ks = 0; ks < 2; ++ks) {
                short8 a = *reinterpret_cast<const short8*>(
                    (char*)Ks + (16 * f + lq) * 128 + ((ks * 64 + 16 * lg) ^ swzr));
                d = __builtin_amdgcn_mfma_f32_16x16x32_bf16(a, qw[ks], d, 0, 0, 0);
            }
            dac[f] = d;
        }
        __builtin_amdgcn_s_setprio(0);

        // ---- bulk softmax: lane owns q=lq, keys {16f+4lg+r}; rel-shift on read
        const bool fullTile = (i0 + 16 * w + MLEN - j0) >= 63;  // wave-uniform
        float sv[4][4];
        float mx = NEGF;
        if (fullTile) {
            #pragma unroll
            for (int f = 0; f < 4; ++f)
                #pragma unroll
                for (int r = 0; r < 4; ++r) {
                    int k = 16 * f + 4 * lg + r;
                    float bd = bf2f(SbW[lq * 84 + k - lq + 15]);
                    float x = (dac[f][r] + bd) * 0.125f;
                    sv[f][r] = x;
                    mx = fmaxf(mx, x);
                }
        } else {
            const int bound = i0 + 16 * w + lq + MLEN - j0;     // keys k <= bound
            #pragma unroll
            for (int f = 0; f < 4; ++f)
                #pragma unroll
                for (int r = 0; r < 4; ++r) {
                    int k = 16 * f + 4 * lg + r;
                    float bd = bf2f(SbW[lq * 84 + k - lq + 15]);
                    float x = (k <= bound) ? (dac[f][r] + bd) * 0.125f : NEGF;
                    sv[f][r] = x;
                    mx = fmaxf(mx, x);
                }
        }
        mx = fmaxf(mx, __shfl_xor(mx, 16));
        mx = fmaxf(mx, __shfl_xor(mx, 32));
        float m_new = fmaxf(m_run, mx);
        float alpha = __expf(m_run - m_new);
        float ps = 0.f;
        #pragma unroll
        for (int f = 0; f < 4; ++f) {
            s16x4 pk;
            #pragma unroll
            for (int r = 0; r < 4; ++r) {
                float p = __expf(sv[f][r] - m_new);
                ps += p;
                pk[r] = (short)f2bf(p);
            }
            // key-block kb = 4f+lg, swizzled kb' = kb ^ ((lq&7)<<1), 8B store
            *reinterpret_cast<s16x4*>(
                (char*)PsW + lq * 128 + (((4 * f + lg) ^ ((lq & 7) << 1)) << 3)) = pk;
        }
        ps += __shfl_xor(ps, 16);
        ps += __shfl_xor(ps, 32);
        l_run = l_run * alpha + ps;
        m_run = m_new;

        // ---- PV: acc[q'][d] = alpha*acc + P@V
        float alr[4];
        #pragma unroll
        for (int r = 0; r < 4; ++r) alr[r] = __shfl(alpha, 20 * lg + r);
        __builtin_amdgcn_s_setprio(1);
        #pragma unroll
        for (int df = 0; df < 4; ++df) {
            f32x4 a = acc[df];
            #pragma unroll
            for (int r = 0; r < 4; ++r) a[r] *= alr[r];
            #pragma unroll
            for (int ks = 0; ks < 2; ++ks) {
                short8 pa = *reinterpret_cast<const short8*>(
                    (char*)PsW + lq * 128 + ((ks * 64 + 16 * lg) ^ swzr));
                short8 vb = *reinterpret_cast<const short8*>(
                    (char*)Vt + (16 * df + lq) * 128 + ((ks * 64 + 16 * lg) ^ swzr));
                a = __builtin_amdgcn_mfma_f32_16x16x32_bf16(pa, vb, a, 0, 0, 0);
            }
            acc[df] = a;
        }
        __builtin_amdgcn_s_setprio(0);
    }

    // ---- epilogue: 1/l via shuffle, D rows q'=4lg+r, col d=16df+lq
    float inv[4];
    #pragma unroll
    for (int r = 0; r < 4; ++r) inv[r] = 1.f / __shfl(l_run, 20 * lg + r);
    #pragma unroll
    for (int df = 0; df < 4; ++df) {
        #pragma unroll
        for (int r = 0; r < 4; ++r) {
            const int il = 16 * w + 4 * lg + r;
            float o = acc[df][r] * inv[r];
            vec[((size_t)((i0 + il) * BSZ + b)) * DM + n * 64 + 16 * df + lq] = f2bf(o);
        }
    }
}

// ---------------- Residual + LayerNorm (1 or 2 extra residual streams) -------
template<int NRES, bool WB>
__global__ __launch_bounds__(256) void ln_res_kernel(
    const float* __restrict__ x, const float* __restrict__ res,
    const float* __restrict__ res2,
    const float* __restrict__ g, const float* __restrict__ bta,
    float* __restrict__ out, u16* __restrict__ outb)
{
    const int row = blockIdx.x;
    const int t = threadIdx.x;
    const int lane = t & 63, wv = t >> 6;
    __shared__ float red0[4], red1[4];

    float4 a = ldg4(&x[(size_t)row * DM + t * 4]);
    float4 b = ldg4(&res[(size_t)row * DM + t * 4]);
    float v0 = a.x + b.x, v1 = a.y + b.y, v2 = a.z + b.z, v3 = a.w + b.w;
    if constexpr (NRES == 2) {
        float4 c = ldg4(&res2[(size_t)row * DM + t * 4]);
        v0 += c.x; v1 += c.y; v2 += c.z; v3 += c.w;
    }
    float s = v0 + v1 + v2 + v3;
    #pragma unroll
    for (int o = 32; o; o >>= 1) s += __shfl_xor(s, o);
    if (lane == 0) red0[wv] = s;
    __syncthreads();
    float mu = (red0[0] + red0[1] + red0[2] + red0[3]) * (1.f / DM);
    float d0 = v0 - mu, d1 = v1 - mu, d2 = v2 - mu, d3 = v3 - mu;
    float q = d0*d0 + d1*d1 + d2*d2 + d3*d3;
    #pragma unroll
    for (int o = 32; o; o >>= 1) q += __shfl_xor(q, o);
    if (lane == 0) red1[wv] = q;
    __syncthreads();
    float var = (red1[0] + red1[1] + red1[2] + red1[3]) * (1.f / DM);
    float rs = rsqrtf(var + 1e-5f);
    float4 gv = ldg4(&g[t * 4]);
    float4 bv = ldg4(&bta[t * 4]);
    float o0 = d0 * rs * gv.x + bv.x;
    float o1 = d1 * rs * gv.y + bv.y;
    float o2 = d2 * rs * gv.z + bv.z;
    float o3 = d3 * rs * gv.w + bv.w;
    float4 o4 = make_float4(o0, o1, o2, o3);
    *reinterpret_cast<float4*>(&out[(size_t)row * DM + t * 4]) = o4;
    if constexpr (WB) {
        u16 ob[4] = { f2bf(o0), f2bf(o1), f2bf(o2), f2bf(o3) };
        *reinterpret_cast<uint2*>(&outb[(size_t)row * DM + t * 4]) = *reinterpret_cast<uint2*>(ob);
    }
}

// ---------------- launch ------------------------------------------------------
extern "C" void kernel_launch(void* const* d_in, const int* in_sizes, int n_in,
                              void* d_out, int out_size, void* d_ws, size_t ws_size,
                              hipStream_t stream) {
    const float* w     = (const float*)d_in[0];
    const float* r     = (const float*)d_in[1];
    const float* mems  = (const float*)d_in[2];
    const float* w_qkv = (const float*)d_in[3];
    const float* w_r   = (const float*)d_in[4];
    const float* w_o   = (const float*)d_in[5];
    const float* rwb   = (const float*)d_in[6];
    const float* rrb   = (const float*)d_in[7];
    const float* ln1g  = (const float*)d_in[8];
    const float* ln1b  = (const float*)d_in[9];
    const float* ffw1  = (const float*)d_in[10];
    const float* ffb1  = (const float*)d_in[11];
    const float* ffw2  = (const float*)d_in[12];
    const float* ffb2  = (const float*)d_in[13];
    const float* ln2g  = (const float*)d_in[14];
    const float* ln2b  = (const float*)d_in[15];
    (void)in_sizes; (void)n_in; (void)out_size; (void)ws_size;

    char* p = (char*)d_ws;
    auto alloc = [&](size_t bytes) { char* q = p; p += (bytes + 255) & ~(size_t)255; return q; };
    u16* catB   = (u16*)alloc((size_t)8192 * 1024 * 2);   // reused as Vg after QKV GEMM
    u16* rB     = (u16*)alloc((size_t)1024 * 1024 * 2);
    u16* qkvT   = (u16*)alloc((size_t)3072 * 1024 * 2);
    u16* wrT    = (u16*)alloc((size_t)1024 * 1024 * 2);
    u16* woT    = (u16*)alloc((size_t)1024 * 1024 * 2);
    u16* f1T    = (u16*)alloc((size_t)4096 * 1024 * 2);
    u16* f2T    = (u16*)alloc((size_t)1024 * 4096 * 2);
    u16* heads  = (u16*)alloc((size_t)8192 * 3072 * 2);   // reused as ff2[2] after attn
    u16* rhk    = (u16*)alloc((size_t)1024 * 1024 * 2);
    u16* vec    = (u16*)alloc((size_t)4096 * 1024 * 2);
    u16* hB     = (u16*)alloc((size_t)4096 * 1024 * 2);
    u16* ff1    = (u16*)alloc((size_t)4096 * 4096 * 2);   // doubles as attn_out[2] before ff1
    float* hF   = (float*)alloc((size_t)4096 * 1024 * 4);

    u16* Vg = catB;                       // 8*16*64*1024*2 = 16.78 MB == catB size
    float* attn_out = (float*)ff1;        // 2*4096*1024*4 = 33.55 MB == ff1 size
    float* ff2 = (float*)heads;           // 2*4096*1024*4 <= heads size
    float* outp = (float*)d_out;

    // casts + fused weight transposes
    cast2_kernel<<<8192, 256, 0, stream>>>(mems, w, 4096 * 1024, catB, 8192 * 1024);
    cast2_kernel<<<1024, 256, 0, stream>>>(r, r, 1024 * 1024, rB, 1024 * 1024);
    transpose_all<<<13312, 256, 0, stream>>>(w_qkv, qkvT, w_r, wrT, w_o, woT,
                                             ffw1, f1T, ffw2, f2T);

    // 1. heads = cat @ w_qkv
    gemm_mfma<false, false, true><<<dim3(24, 64), 256, 0, stream>>>(
        catB, qkvT, nullptr, nullptr, heads, 8192, 3072, 1024, 1024, 1024);
    // 2. V transpose (catB dead -> Vg aliases it)
    v_transpose<<<dim3(128, 16), 256, 0, stream>>>(heads, Vg);
    // 3. rhk = r @ w_r
    gemm_mfma<false, false, true><<<dim3(8, 8), 256, 0, stream>>>(
        rB, wrT, nullptr, nullptr, rhk, 1024, 1024, 1024, 1024, 1024);
    // 4. attention
    attn_mfma<<<dim3(BSZ * NH, QLEN / 128), 512, 0, stream>>>(
        heads, Vg, rhk, rwb, rrb, vec);
    // 5. attn_out = vec @ w_o, split-K x2 (fp32 partials)
    gemm_mfma<false, false, false><<<dim3(8, 32, 2), 256, 0, stream>>>(
        vec, woT, nullptr, attn_out, nullptr, 4096, 1024, 512, 1024, 1024);
    // 6. h = LN(w + ao0 + ao1), keep fp32 + bf16
    ln_res_kernel<2, true><<<4096, 256, 0, stream>>>(
        w, attn_out, attn_out + (size_t)4096 * 1024, ln1g, ln1b, hF, hB);
    // 7. ff1 = relu(h @ ff_w1 + b1) (bf16 out; overwrites attn_out region)
    gemm_mfma<true, true, true><<<dim3(32, 32), 256, 0, stream>>>(
        hB, f1T, ffb1, nullptr, ff1, 4096, 4096, 1024, 1024, 1024);
    // 8. ff2 = ff1 @ ff_w2 + b2, split-K x2 (fp32 partials; overwrites heads)
    gemm_mfma<true, false, false><<<dim3(8, 32, 2), 256, 0, stream>>>(
        ff1, f2T, ffb2, ff2, nullptr, 4096, 1024, 2048, 4096, 4096);
    // 9. out = LN(h + ff2a + ff2b)
    ln_res_kernel<2, false><<<4096, 256, 0, stream>>>(
        hF, ff2, ff2 + (size_t)4096 * 1024, ln2g, ln2b, outp, nullptr);
}

// Round 6
// 328.368 us; speedup vs baseline: 10.5347x; 1.0490x over previous
//
#include <hip/hip_runtime.h>
#include <hip/hip_bf16.h>

#define QLEN 512
#define MLEN 512
#define KLEN 1024
#define BSZ 8
#define DM 1024
#define NH 16
#define DH 64
#define DI 4096
#define NEGF (-1e30f)

typedef unsigned short u16;
typedef __attribute__((ext_vector_type(8))) short short8;
typedef __attribute__((ext_vector_type(4))) short s16x4;
typedef __attribute__((ext_vector_type(4))) float f32x4;

__device__ __forceinline__ float bf2f(u16 u) {
    union { unsigned i; float f; } x; x.i = ((unsigned)u) << 16; return x.f;
}
__device__ __forceinline__ u16 f2bf(float f) {
    __hip_bfloat16 h = __float2bfloat16(f);
    return *reinterpret_cast<u16*>(&h);
}
__device__ __forceinline__ float4 ldg4(const float* p) {
    return *reinterpret_cast<const float4*>(p);
}
// async global->LDS DMA, 16B per lane; LDS dest = wave-uniform base (+ lane*16 by HW)
__device__ __forceinline__ void gload16(const void* g, void* l) {
    __builtin_amdgcn_global_load_lds(
        (const __attribute__((address_space(1))) void*)g,
        (__attribute__((address_space(3))) void*)l, 16, 0, 0);
}

// ---------------- cast fp32 -> bf16, two-source concat along flat index -----
__global__ __launch_bounds__(256) void cast2_kernel(
    const float* __restrict__ a, const float* __restrict__ b, int splitE,
    u16* __restrict__ out, int n)
{
    int idx = (blockIdx.x * 256 + threadIdx.x) * 4;
    if (idx >= n) return;
    const float* src = (idx < splitE) ? (a + idx) : (b + (idx - splitE));
    float4 v = ldg4(src);
    u16 o[4] = { f2bf(v.x), f2bf(v.y), f2bf(v.z), f2bf(v.w) };
    *reinterpret_cast<uint2*>(&out[idx]) = *reinterpret_cast<uint2*>(o);
}

// ---------------- fused weight transposes: 5 matrices in one launch ----------
__device__ __forceinline__ void tr32(
    const float* __restrict__ W, u16* __restrict__ WT, int K, int N, int k0, int n0)
{
    __shared__ float tile[32][33];
    const int tx = threadIdx.x & 31, ty = threadIdx.x >> 5;
    #pragma unroll
    for (int j = 0; j < 4; ++j)
        tile[ty + j * 8][tx] = W[(size_t)(k0 + ty + j * 8) * N + n0 + tx];
    __syncthreads();
    #pragma unroll
    for (int j = 0; j < 4; ++j)
        WT[(size_t)(n0 + ty + j * 8) * K + k0 + tx] = f2bf(tile[tx][ty + j * 8]);
}

__global__ __launch_bounds__(256) void transpose_all(
    const float* __restrict__ w_qkv, u16* __restrict__ qkvT,
    const float* __restrict__ w_r,   u16* __restrict__ wrT,
    const float* __restrict__ w_o,   u16* __restrict__ woT,
    const float* __restrict__ ffw1,  u16* __restrict__ f1T,
    const float* __restrict__ ffw2,  u16* __restrict__ f2T)
{
    int id = blockIdx.x;
    if (id < 3072)       { int l = id;        tr32(w_qkv, qkvT, 1024, 3072, (l / 96) * 32, (l % 96) * 32); }
    else if (id < 4096)  { int l = id - 3072; tr32(w_r,   wrT,  1024, 1024, (l / 32) * 32, (l % 32) * 32); }
    else if (id < 5120)  { int l = id - 4096; tr32(w_o,   woT,  1024, 1024, (l / 32) * 32, (l % 32) * 32); }
    else if (id < 9216)  { int l = id - 5120; tr32(ffw1,  f1T,  1024, 4096, (l / 128) * 32, (l % 128) * 32); }
    else                 { int l = id - 9216; tr32(ffw2,  f2T,  4096, 1024, (l / 32) * 32, (l % 32) * 32); }
}

// ---------------- V transpose: heads V-part -> Vg[(b,h)][d][key] bf16 --------
__global__ __launch_bounds__(256) void v_transpose(
    const u16* __restrict__ heads, u16* __restrict__ Vg)
{
    const int bn = blockIdx.x;            // b*16+n
    const int b = bn >> 4, n = bn & 15;
    const int kt = blockIdx.y;            // 64-key tile
    const int t = threadIdx.x;
    __shared__ u16 L[64 * 64];            // [key][d], col-swizzled

    #pragma unroll
    for (int rep = 0; rep < 2; ++rep) {
        int idx = t + rep * 256;
        int key = idx >> 3, dc = (idx & 7) * 8;
        short8 v = *reinterpret_cast<const short8*>(
            &heads[((size_t)((kt * 64 + key) * BSZ + b)) * 3072 + 2048 + n * 64 + dc]);
        *reinterpret_cast<short8*>((char*)L + key * 128 + ((dc * 2) ^ ((key & 7) << 4))) = v;
    }
    __syncthreads();
    #pragma unroll
    for (int rep = 0; rep < 2; ++rep) {
        int idx = t + rep * 256;
        int d = idx >> 3, kc = (idx & 7) * 8;
        short8 o;
        #pragma unroll
        for (int e = 0; e < 8; ++e)
            o[e] = *(const short*)((char*)L + (kc + e) * 128 + ((d * 2) ^ (((kc + e) & 7) << 4)));
        *reinterpret_cast<short8*>(&Vg[((size_t)(bn * 64 + d)) * KLEN + kt * 64 + kc]) = o;
    }
}

// ---------------- bf16 MFMA GEMM (m97 structure, 128x128): small GEMMs -------
template<bool BIAS, bool RELU, bool OUTBF>
__global__ __launch_bounds__(256) void gemm_mfma(
    const u16* __restrict__ A, const u16* __restrict__ BT,
    const float* __restrict__ bias,
    float* __restrict__ Cf, u16* __restrict__ Cb,
    int M, int N, int K, int lda, int ldb)
{
    __shared__ u16 As[128 * 64];
    __shared__ u16 Bs[128 * 64];
    const int bm = blockIdx.y * 128, bn = blockIdx.x * 128;
    const int z = blockIdx.z;
    A  += (size_t)z * K;
    BT += (size_t)z * K;
    const size_t zoff = (size_t)z * M * N;
    const int t = threadIdx.x;
    const int w = t >> 6, l = t & 63, lg = l >> 4, lq = l & 15;
    const int wm = (w >> 1) * 64, wn = (w & 1) * 64;
    const int r8 = l >> 3, slot = l & 7;
    const int gcol = (slot * 16) ^ (r8 << 4);

    f32x4 acc[4][4];
    #pragma unroll
    for (int x = 0; x < 4; ++x)
        #pragma unroll
        for (int y = 0; y < 4; ++y)
            acc[x][y] = (f32x4){0.f, 0.f, 0.f, 0.f};

    const int swzr = (lq & 7) << 4;

    for (int k0 = 0; k0 < K; k0 += 64) {
        __syncthreads();
        #pragma unroll
        for (int it = 0; it < 4; ++it) {
            const int base_row = w * 8 + it * 32;
            gload16((const char*)A + (((size_t)(bm + base_row + r8) * lda + k0) << 1) + gcol,
                    (char*)As + base_row * 128);
            gload16((const char*)BT + (((size_t)(bn + base_row + r8) * ldb + k0) << 1) + gcol,
                    (char*)Bs + base_row * 128);
        }
        __syncthreads();
        #pragma unroll
        for (int ks = 0; ks < 2; ++ks) {
            const int cb = (ks * 64 + 16 * lg) ^ swzr;
            short8 af[4], bf_[4];
            #pragma unroll
            for (int x = 0; x < 4; ++x)
                af[x] = *reinterpret_cast<const short8*>((char*)As + (wm + 16 * x + lq) * 128 + cb);
            #pragma unroll
            for (int y = 0; y < 4; ++y)
                bf_[y] = *reinterpret_cast<const short8*>((char*)Bs + (wn + 16 * y + lq) * 128 + cb);
            #pragma unroll
            for (int x = 0; x < 4; ++x)
                #pragma unroll
                for (int y = 0; y < 4; ++y)
                    acc[x][y] = __builtin_amdgcn_mfma_f32_16x16x32_bf16(af[x], bf_[y], acc[x][y], 0, 0, 0);
        }
    }
    #pragma unroll
    for (int x = 0; x < 4; ++x) {
        #pragma unroll
        for (int y = 0; y < 4; ++y) {
            const int col = bn + wn + 16 * y + lq;
            #pragma unroll
            for (int r = 0; r < 4; ++r) {
                const int row = bm + wm + 16 * x + 4 * lg + r;
                float v = acc[x][y][r];
                if constexpr (BIAS) { if (z == 0) v += bias[col]; }
                if constexpr (RELU) v = fmaxf(v, 0.f);
                if constexpr (OUTBF) Cb[zoff + (size_t)row * N + col] = f2bf(v);
                else                 Cf[zoff + (size_t)row * N + col] = v;
            }
        }
    }
}

// ---------------- deep-pipeline bf16 MFMA GEMM (round-6): big GEMMs ----------
// BM=256, BN=128, BK=64; 512 threads = 8 waves (4x2), per-wave 64x64 (4x4 frags).
// 3 LDS buffers (144 KB), depth-2 prefetch via global_load_lds; counted
// s_waitcnt vmcnt(6) + raw s_barrier (ONE barrier per K-tile, no drain except
// the final tile). WAR safe: buffer (t+2)%3 was last read in tile t-1, which
// completed before this tile's barrier. RAW safe: every wave waits its own
// vmcnt then barriers, so all waves' loads for tile t have landed.
template<bool BIAS, bool RELU, bool OUTBF>
__global__ __launch_bounds__(512, 2) void gemm_deep(
    const u16* __restrict__ A, const u16* __restrict__ BT,
    const float* __restrict__ bias,
    float* __restrict__ Cf, u16* __restrict__ Cb,
    int M, int N, int K, int lda, int ldb)
{
    __shared__ u16 lds[3 * 24576];        // 3 x (A 256x64 + B 128x64) = 144 KB
    const int bm = blockIdx.y * 256, bn = blockIdx.x * 128;
    const int z = blockIdx.z;
    A  += (size_t)z * K;
    BT += (size_t)z * K;
    const size_t zoff = (size_t)z * M * N;
    const int t = threadIdx.x;            // 0..511
    const int w = t >> 6, l = t & 63, lg = l >> 4, lq = l & 15;
    const int wm = (w >> 1) * 64;         // 4 M-groups
    const int wn = (w & 1) * 64;          // 2 N-groups
    const int srow = t >> 3, slot = t & 7;
    const int gcol = (slot * 16) ^ ((srow & 7) << 4);
    const int swzr = (lq & 7) << 4;

    // stage K-tile kt into buffer buf: A 4 issues (256 rows), B 2 issues (128)
    auto stage_tile = [&](int kt, int buf) {
        const int k0 = kt * 64;
        char* Ab = (char*)lds + buf * 49152 + w * 1024;
        char* Bb = (char*)lds + buf * 49152 + 32768 + w * 1024;
        #pragma unroll
        for (int i = 0; i < 4; ++i)
            gload16((const char*)A + (((size_t)(bm + i * 64 + srow) * lda + k0) << 1) + gcol,
                    Ab + i * 8192);
        #pragma unroll
        for (int i = 0; i < 2; ++i)
            gload16((const char*)BT + (((size_t)(bn + i * 64 + srow) * ldb + k0) << 1) + gcol,
                    Bb + i * 8192);
    };

    f32x4 acc[4][4];
    #pragma unroll
    for (int x = 0; x < 4; ++x)
        #pragma unroll
        for (int y = 0; y < 4; ++y)
            acc[x][y] = (f32x4){0.f, 0.f, 0.f, 0.f};

    const int NT = K >> 6;
    stage_tile(0, 0);
    stage_tile(1, 1);

    for (int kt = 0; kt < NT; ++kt) {
        if (kt < NT - 1) asm volatile("s_waitcnt vmcnt(6)" ::: "memory");
        else             asm volatile("s_waitcnt vmcnt(0)" ::: "memory");
        __builtin_amdgcn_s_barrier();
        __builtin_amdgcn_sched_barrier(0);
        if (kt + 2 < NT) stage_tile(kt + 2, (kt + 2) % 3);

        const char* Ab = (const char*)lds + (kt % 3) * 49152;
        const char* Bb = Ab + 32768;
        #pragma unroll
        for (int ks = 0; ks < 2; ++ks) {
            const int cb = (ks * 64 + 16 * lg) ^ swzr;
            short8 af[4], bf_[4];
            #pragma unroll
            for (int x = 0; x < 4; ++x)
                af[x] = *reinterpret_cast<const short8*>(Ab + (wm + 16 * x + lq) * 128 + cb);
            #pragma unroll
            for (int y = 0; y < 4; ++y)
                bf_[y] = *reinterpret_cast<const short8*>(Bb + (wn + 16 * y + lq) * 128 + cb);
            __builtin_amdgcn_s_setprio(1);
            #pragma unroll
            for (int x = 0; x < 4; ++x)
                #pragma unroll
                for (int y = 0; y < 4; ++y)
                    acc[x][y] = __builtin_amdgcn_mfma_f32_16x16x32_bf16(af[x], bf_[y], acc[x][y], 0, 0, 0);
            __builtin_amdgcn_s_setprio(0);
        }
    }

    #pragma unroll
    for (int x = 0; x < 4; ++x) {
        #pragma unroll
        for (int y = 0; y < 4; ++y) {
            const int col = bn + wn + 16 * y + lq;
            #pragma unroll
            for (int r = 0; r < 4; ++r) {
                const int row = bm + wm + 16 * x + 4 * lg + r;
                float v = acc[x][y][r];
                if constexpr (BIAS) { if (z == 0) v += bias[col]; }
                if constexpr (RELU) v = fmaxf(v, 0.f);
                if constexpr (OUTBF) Cb[zoff + (size_t)row * N + col] = f2bf(v);
                else                 Cf[zoff + (size_t)row * N + col] = v;
            }
        }
    }
}

// ---------------- MFMA flash relative attention (unchanged from round 5) -----
__global__ __launch_bounds__(512, 4) void attn_mfma(
    const u16* __restrict__ heads,   // bf16 [KLEN*BSZ][3*NH*DH]
    const u16* __restrict__ Vg,      // bf16 [(b,h)][DH][KLEN]
    const u16* __restrict__ rhk,     // bf16 [KLEN][NH*DH]
    const float* __restrict__ rwb, const float* __restrict__ rrb,
    u16* __restrict__ vec)           // bf16 [QLEN*BSZ][NH*DH]
{
    const int b = blockIdx.x >> 4;
    const int n = blockIdx.x & 15;
    const int i0 = (3 - blockIdx.y) * 128;      // long blocks first
    const int t = threadIdx.x;
    const int w = t >> 6;                        // 0..7
    const int l = t & 63;
    const int lg = l >> 4, lq = l & 15;
    const int r8 = l >> 3, sl = l & 7;

    __shared__ u16 Ks[64 * 64];
    __shared__ u16 Vt[64 * 64];
    __shared__ u16 Rs[192 * 64];
    __shared__ u16 SbO[8 * 16 * 84];
    __shared__ u16 Ps[8 * 16 * 64];

    u16* SbW = SbO + w * 16 * 84;
    u16* PsW = Ps + w * 16 * 64;
    const int swzr = (lq & 7) << 4;
    const int stg_swz = (sl * 16) ^ (r8 << 4);

    short8 qw[2], qr[2];
    {
        const int qrow = i0 + 16 * w + lq;
        const size_t gbase = ((size_t)((MLEN + qrow) * BSZ + b)) * 3072 + n * 64;
        #pragma unroll
        for (int ks = 0; ks < 2; ++ks) {
            short8 qv = *reinterpret_cast<const short8*>(&heads[gbase + ks * 32 + 8 * lg]);
            short8 xw, xr;
            #pragma unroll
            for (int e = 0; e < 8; ++e) {
                float f = bf2f((u16)qv[e]);
                int d = ks * 32 + 8 * lg + e;
                xw[e] = (short)f2bf(f + rwb[n * 64 + d]);
                xr[e] = (short)f2bf(f + rrb[n * 64 + d]);
            }
            qw[ks] = xw; qr[ks] = xr;
        }
    }

    float m_run = NEGF, l_run = 0.f;
    f32x4 acc[4];
    #pragma unroll
    for (int df = 0; df < 4; ++df) acc[df] = (f32x4){0.f, 0.f, 0.f, 0.f};

    const int s0 = 112 - 16 * w;
    const int ntiles = i0 / 64 + 10;

    for (int tile = 0; tile < ntiles; ++tile) {
        const int j0 = tile << 6;
        __syncthreads();
        gload16((const char*)heads
                    + (((size_t)((j0 + w * 8 + r8) * BSZ + b)) * 3072 + 1024 + n * 64) * 2
                    + stg_swz,
                (char*)Ks + w * 1024);
        gload16((const char*)Vg
                    + (((size_t)(blockIdx.x * 64 + w * 8 + r8)) * KLEN + j0) * 2
                    + stg_swz,
                (char*)Vt + w * 1024);
        const int obase = j0 - i0 + 384;
        #pragma unroll
        for (int pass = 0; pass < 3; ++pass) {
            int row = pass * 64 + w * 8 + r8;
            int o = obase + row;
            o = o > (KLEN - 1) ? (KLEN - 1) : o;
            gload16((const char*)rhk + ((size_t)o * 1024 + n * 64) * 2 + stg_swz,
                    (char*)Rs + pass * 8192 + w * 1024);
        }
        __syncthreads();

        __builtin_amdgcn_s_setprio(1);
        #pragma unroll
        for (int ff = 0; ff < 5; ++ff) {
            f32x4 d = (f32x4){0.f, 0.f, 0.f, 0.f};
            #pragma unroll
            for (int ks = 0; ks < 2; ++ks) {
                short8 a = *reinterpret_cast<const short8*>(
                    (char*)Rs + (s0 + 16 * ff + lq) * 128 + ((ks * 64 + 16 * lg) ^ swzr));
                d = __builtin_amdgcn_mfma_f32_16x16x32_bf16(a, qr[ks], d, 0, 0, 0);
            }
            s16x4 pk;
            #pragma unroll
            for (int r = 0; r < 4; ++r) pk[r] = (short)f2bf(d[r]);
            *reinterpret_cast<s16x4*>(&SbW[lq * 84 + 16 * ff + 4 * lg]) = pk;
        }
        f32x4 dac[4];
        #pragma unroll
        for (int f = 0; f < 4; ++f) {
            f32x4 d = (f32x4){0.f, 0.f, 0.f, 0.f};
            #pragma unroll
            for (int ks = 0; ks < 2; ++ks) {
                short8 a = *reinterpret_cast<const short8*>(
                    (char*)Ks + (16 * f + lq) * 128 + ((ks * 64 + 16 * lg) ^ swzr));
                d = __builtin_amdgcn_mfma_f32_16x16x32_bf16(a, qw[ks], d, 0, 0, 0);
            }
            dac[f] = d;
        }
        __builtin_amdgcn_s_setprio(0);

        const bool fullTile = (i0 + 16 * w + MLEN - j0) >= 63;
        float sv[4][4];
        float mx = NEGF;
        if (fullTile) {
            #pragma unroll
            for (int f = 0; f < 4; ++f)
                #pragma unroll
                for (int r = 0; r < 4; ++r) {
                    int k = 16 * f + 4 * lg + r;
                    float bd = bf2f(SbW[lq * 84 + k - lq + 15]);
                    float x = (dac[f][r] + bd) * 0.125f;
                    sv[f][r] = x;
                    mx = fmaxf(mx, x);
                }
        } else {
            const int bound = i0 + 16 * w + lq + MLEN - j0;
            #pragma unroll
            for (int f = 0; f < 4; ++f)
                #pragma unroll
                for (int r = 0; r < 4; ++r) {
                    int k = 16 * f + 4 * lg + r;
                    float bd = bf2f(SbW[lq * 84 + k - lq + 15]);
                    float x = (k <= bound) ? (dac[f][r] + bd) * 0.125f : NEGF;
                    sv[f][r] = x;
                    mx = fmaxf(mx, x);
                }
        }
        mx = fmaxf(mx, __shfl_xor(mx, 16));
        mx = fmaxf(mx, __shfl_xor(mx, 32));
        float m_new = fmaxf(m_run, mx);
        float alpha = __expf(m_run - m_new);
        float ps = 0.f;
        #pragma unroll
        for (int f = 0; f < 4; ++f) {
            s16x4 pk;
            #pragma unroll
            for (int r = 0; r < 4; ++r) {
                float p = __expf(sv[f][r] - m_new);
                ps += p;
                pk[r] = (short)f2bf(p);
            }
            *reinterpret_cast<s16x4*>(
                (char*)PsW + lq * 128 + (((4 * f + lg) ^ ((lq & 7) << 1)) << 3)) = pk;
        }
        ps += __shfl_xor(ps, 16);
        ps += __shfl_xor(ps, 32);
        l_run = l_run * alpha + ps;
        m_run = m_new;

        float alr[4];
        #pragma unroll
        for (int r = 0; r < 4; ++r) alr[r] = __shfl(alpha, 20 * lg + r);
        __builtin_amdgcn_s_setprio(1);
        #pragma unroll
        for (int df = 0; df < 4; ++df) {
            f32x4 a = acc[df];
            #pragma unroll
            for (int r = 0; r < 4; ++r) a[r] *= alr[r];
            #pragma unroll
            for (int ks = 0; ks < 2; ++ks) {
                short8 pa = *reinterpret_cast<const short8*>(
                    (char*)PsW + lq * 128 + ((ks * 64 + 16 * lg) ^ swzr));
                short8 vb = *reinterpret_cast<const short8*>(
                    (char*)Vt + (16 * df + lq) * 128 + ((ks * 64 + 16 * lg) ^ swzr));
                a = __builtin_amdgcn_mfma_f32_16x16x32_bf16(pa, vb, a, 0, 0, 0);
            }
            acc[df] = a;
        }
        __builtin_amdgcn_s_setprio(0);
    }

    float inv[4];
    #pragma unroll
    for (int r = 0; r < 4; ++r) inv[r] = 1.f / __shfl(l_run, 20 * lg + r);
    #pragma unroll
    for (int df = 0; df < 4; ++df) {
        #pragma unroll
        for (int r = 0; r < 4; ++r) {
            const int il = 16 * w + 4 * lg + r;
            float o = acc[df][r] * inv[r];
            vec[((size_t)((i0 + il) * BSZ + b)) * DM + n * 64 + 16 * df + lq] = f2bf(o);
        }
    }
}

// ---------------- Residual + LayerNorm (1 or 2 extra residual streams) -------
template<int NRES, bool WB>
__global__ __launch_bounds__(256) void ln_res_kernel(
    const float* __restrict__ x, const float* __restrict__ res,
    const float* __restrict__ res2,
    const float* __restrict__ g, const float* __restrict__ bta,
    float* __restrict__ out, u16* __restrict__ outb)
{
    const int row = blockIdx.x;
    const int t = threadIdx.x;
    const int lane = t & 63, wv = t >> 6;
    __shared__ float red0[4], red1[4];

    float4 a = ldg4(&x[(size_t)row * DM + t * 4]);
    float4 b = ldg4(&res[(size_t)row * DM + t * 4]);
    float v0 = a.x + b.x, v1 = a.y + b.y, v2 = a.z + b.z, v3 = a.w + b.w;
    if constexpr (NRES == 2) {
        float4 c = ldg4(&res2[(size_t)row * DM + t * 4]);
        v0 += c.x; v1 += c.y; v2 += c.z; v3 += c.w;
    }
    float s = v0 + v1 + v2 + v3;
    #pragma unroll
    for (int o = 32; o; o >>= 1) s += __shfl_xor(s, o);
    if (lane == 0) red0[wv] = s;
    __syncthreads();
    float mu = (red0[0] + red0[1] + red0[2] + red0[3]) * (1.f / DM);
    float d0 = v0 - mu, d1 = v1 - mu, d2 = v2 - mu, d3 = v3 - mu;
    float q = d0*d0 + d1*d1 + d2*d2 + d3*d3;
    #pragma unroll
    for (int o = 32; o; o >>= 1) q += __shfl_xor(q, o);
    if (lane == 0) red1[wv] = q;
    __syncthreads();
    float var = (red1[0] + red1[1] + red1[2] + red1[3]) * (1.f / DM);
    float rs = rsqrtf(var + 1e-5f);
    float4 gv = ldg4(&g[t * 4]);
    float4 bv = ldg4(&bta[t * 4]);
    float o0 = d0 * rs * gv.x + bv.x;
    float o1 = d1 * rs * gv.y + bv.y;
    float o2 = d2 * rs * gv.z + bv.z;
    float o3 = d3 * rs * gv.w + bv.w;
    float4 o4 = make_float4(o0, o1, o2, o3);
    *reinterpret_cast<float4*>(&out[(size_t)row * DM + t * 4]) = o4;
    if constexpr (WB) {
        u16 ob[4] = { f2bf(o0), f2bf(o1), f2bf(o2), f2bf(o3) };
        *reinterpret_cast<uint2*>(&outb[(size_t)row * DM + t * 4]) = *reinterpret_cast<uint2*>(ob);
    }
}

// ---------------- launch ------------------------------------------------------
extern "C" void kernel_launch(void* const* d_in, const int* in_sizes, int n_in,
                              void* d_out, int out_size, void* d_ws, size_t ws_size,
                              hipStream_t stream) {
    const float* w     = (const float*)d_in[0];
    const float* r     = (const float*)d_in[1];
    const float* mems  = (const float*)d_in[2];
    const float* w_qkv = (const float*)d_in[3];
    const float* w_r   = (const float*)d_in[4];
    const float* w_o   = (const float*)d_in[5];
    const float* rwb   = (const float*)d_in[6];
    const float* rrb   = (const float*)d_in[7];
    const float* ln1g  = (const float*)d_in[8];
    const float* ln1b  = (const float*)d_in[9];
    const float* ffw1  = (const float*)d_in[10];
    const float* ffb1  = (const float*)d_in[11];
    const float* ffw2  = (const float*)d_in[12];
    const float* ffb2  = (const float*)d_in[13];
    const float* ln2g  = (const float*)d_in[14];
    const float* ln2b  = (const float*)d_in[15];
    (void)in_sizes; (void)n_in; (void)out_size; (void)ws_size;

    char* p = (char*)d_ws;
    auto alloc = [&](size_t bytes) { char* q = p; p += (bytes + 255) & ~(size_t)255; return q; };
    u16* catB   = (u16*)alloc((size_t)8192 * 1024 * 2);   // reused as Vg after QKV GEMM
    u16* rB     = (u16*)alloc((size_t)1024 * 1024 * 2);
    u16* qkvT   = (u16*)alloc((size_t)3072 * 1024 * 2);
    u16* wrT    = (u16*)alloc((size_t)1024 * 1024 * 2);
    u16* woT    = (u16*)alloc((size_t)1024 * 1024 * 2);
    u16* f1T    = (u16*)alloc((size_t)4096 * 1024 * 2);
    u16* f2T    = (u16*)alloc((size_t)1024 * 4096 * 2);
    u16* heads  = (u16*)alloc((size_t)8192 * 3072 * 2);   // reused as ff2[2] after attn
    u16* rhk    = (u16*)alloc((size_t)1024 * 1024 * 2);
    u16* vec    = (u16*)alloc((size_t)4096 * 1024 * 2);
    u16* hB     = (u16*)alloc((size_t)4096 * 1024 * 2);
    u16* ff1    = (u16*)alloc((size_t)4096 * 4096 * 2);   // doubles as attn_out[2] before ff1
    float* hF   = (float*)alloc((size_t)4096 * 1024 * 4);

    u16* Vg = catB;
    float* attn_out = (float*)ff1;
    float* ff2 = (float*)heads;
    float* outp = (float*)d_out;

    // casts + fused weight transposes
    cast2_kernel<<<8192, 256, 0, stream>>>(mems, w, 4096 * 1024, catB, 8192 * 1024);
    cast2_kernel<<<1024, 256, 0, stream>>>(r, r, 1024 * 1024, rB, 1024 * 1024);
    transpose_all<<<13312, 256, 0, stream>>>(w_qkv, qkvT, w_r, wrT, w_o, woT,
                                             ffw1, f1T, ffw2, f2T);

    // 1. heads = cat @ w_qkv  (deep pipeline: M=8192, N=3072, K=1024)
    gemm_deep<false, false, true><<<dim3(24, 32), 512, 0, stream>>>(
        catB, qkvT, nullptr, nullptr, heads, 8192, 3072, 1024, 1024, 1024);
    // 2. V transpose (catB dead -> Vg aliases it)
    v_transpose<<<dim3(128, 16), 256, 0, stream>>>(heads, Vg);
    // 3. rhk = r @ w_r (small: keep 128^2 kernel)
    gemm_mfma<false, false, true><<<dim3(8, 8), 256, 0, stream>>>(
        rB, wrT, nullptr, nullptr, rhk, 1024, 1024, 1024, 1024, 1024);
    // 4. attention
    attn_mfma<<<dim3(BSZ * NH, QLEN / 128), 512, 0, stream>>>(
        heads, Vg, rhk, rwb, rrb, vec);
    // 5. attn_out = vec @ w_o, split-K x2 (128^2 kernel: better grid fit)
    gemm_mfma<false, false, false><<<dim3(8, 32, 2), 256, 0, stream>>>(
        vec, woT, nullptr, attn_out, nullptr, 4096, 1024, 512, 1024, 1024);
    // 6. h = LN(w + ao0 + ao1), keep fp32 + bf16
    ln_res_kernel<2, true><<<4096, 256, 0, stream>>>(
        w, attn_out, attn_out + (size_t)4096 * 1024, ln1g, ln1b, hF, hB);
    // 7. ff1 = relu(h @ ff_w1 + b1)  (deep pipeline: 4096x4096x1024)
    gemm_deep<true, true, true><<<dim3(32, 16), 512, 0, stream>>>(
        hB, f1T, ffb1, nullptr, ff1, 4096, 4096, 1024, 1024, 1024);
    // 8. ff2 = ff1 @ ff_w2 + b2, split-K x2 (deep pipeline: 4096x1024x2048 each)
    gemm_deep<true, false, false><<<dim3(8, 16, 2), 512, 0, stream>>>(
        ff1, f2T, ffb2, ff2, nullptr, 4096, 1024, 2048, 4096, 4096);
    // 9. out = LN(h + ff2a + ff2b)
    ln_res_kernel<2, false><<<4096, 256, 0, stream>>>(
        hF, ff2, ff2 + (size_t)4096 * 1024, ln2g, ln2b, outp, nullptr);
}

// Round 7
// 327.562 us; speedup vs baseline: 10.5606x; 1.0025x over previous
//
#include <hip/hip_runtime.h>
#include <hip/hip_bf16.h>

#define QLEN 512
#define MLEN 512
#define KLEN 1024
#define BSZ 8
#define DM 1024
#define NH 16
#define DH 64
#define DI 4096
#define NEGF (-1e30f)

typedef unsigned short u16;
typedef __attribute__((ext_vector_type(8))) short short8;
typedef __attribute__((ext_vector_type(4))) short s16x4;
typedef __attribute__((ext_vector_type(4))) float f32x4;

__device__ __forceinline__ float bf2f(u16 u) {
    union { unsigned i; float f; } x; x.i = ((unsigned)u) << 16; return x.f;
}
__device__ __forceinline__ u16 f2bf(float f) {
    __hip_bfloat16 h = __float2bfloat16(f);
    return *reinterpret_cast<u16*>(&h);
}
__device__ __forceinline__ float4 ldg4(const float* p) {
    return *reinterpret_cast<const float4*>(p);
}
// async global->LDS DMA, 16B per lane; LDS dest = wave-uniform base (+ lane*16 by HW)
__device__ __forceinline__ void gload16(const void* g, void* l) {
    __builtin_amdgcn_global_load_lds(
        (const __attribute__((address_space(1))) void*)g,
        (__attribute__((address_space(3))) void*)l, 16, 0, 0);
}

// ---------------- cast fp32 -> bf16, two-source concat along flat index -----
__global__ __launch_bounds__(256) void cast2_kernel(
    const float* __restrict__ a, const float* __restrict__ b, int splitE,
    u16* __restrict__ out, int n)
{
    int idx = (blockIdx.x * 256 + threadIdx.x) * 4;
    if (idx >= n) return;
    const float* src = (idx < splitE) ? (a + idx) : (b + (idx - splitE));
    float4 v = ldg4(src);
    u16 o[4] = { f2bf(v.x), f2bf(v.y), f2bf(v.z), f2bf(v.w) };
    *reinterpret_cast<uint2*>(&out[idx]) = *reinterpret_cast<uint2*>(o);
}

// ---------------- fused weight transposes: 5 matrices in one launch ----------
__device__ __forceinline__ void tr32(
    const float* __restrict__ W, u16* __restrict__ WT, int K, int N, int k0, int n0)
{
    __shared__ float tile[32][33];
    const int tx = threadIdx.x & 31, ty = threadIdx.x >> 5;
    #pragma unroll
    for (int j = 0; j < 4; ++j)
        tile[ty + j * 8][tx] = W[(size_t)(k0 + ty + j * 8) * N + n0 + tx];
    __syncthreads();
    #pragma unroll
    for (int j = 0; j < 4; ++j)
        WT[(size_t)(n0 + ty + j * 8) * K + k0 + tx] = f2bf(tile[tx][ty + j * 8]);
}

__global__ __launch_bounds__(256) void transpose_all(
    const float* __restrict__ w_qkv, u16* __restrict__ qkvT,
    const float* __restrict__ w_r,   u16* __restrict__ wrT,
    const float* __restrict__ w_o,   u16* __restrict__ woT,
    const float* __restrict__ ffw1,  u16* __restrict__ f1T,
    const float* __restrict__ ffw2,  u16* __restrict__ f2T)
{
    int id = blockIdx.x;
    if (id < 3072)       { int l = id;        tr32(w_qkv, qkvT, 1024, 3072, (l / 96) * 32, (l % 96) * 32); }
    else if (id < 4096)  { int l = id - 3072; tr32(w_r,   wrT,  1024, 1024, (l / 32) * 32, (l % 32) * 32); }
    else if (id < 5120)  { int l = id - 4096; tr32(w_o,   woT,  1024, 1024, (l / 32) * 32, (l % 32) * 32); }
    else if (id < 9216)  { int l = id - 5120; tr32(ffw1,  f1T,  1024, 4096, (l / 128) * 32, (l % 128) * 32); }
    else                 { int l = id - 9216; tr32(ffw2,  f2T,  4096, 1024, (l / 32) * 32, (l % 32) * 32); }
}

// ---------------- V transpose: heads V-part -> Vg[(b,h)][d][key] bf16 --------
__global__ __launch_bounds__(256) void v_transpose(
    const u16* __restrict__ heads, u16* __restrict__ Vg)
{
    const int bn = blockIdx.x;            // b*16+n
    const int b = bn >> 4, n = bn & 15;
    const int kt = blockIdx.y;            // 64-key tile
    const int t = threadIdx.x;
    __shared__ u16 L[64 * 64];            // [key][d], col-swizzled

    #pragma unroll
    for (int rep = 0; rep < 2; ++rep) {
        int idx = t + rep * 256;
        int key = idx >> 3, dc = (idx & 7) * 8;
        short8 v = *reinterpret_cast<const short8*>(
            &heads[((size_t)((kt * 64 + key) * BSZ + b)) * 3072 + 2048 + n * 64 + dc]);
        *reinterpret_cast<short8*>((char*)L + key * 128 + ((dc * 2) ^ ((key & 7) << 4))) = v;
    }
    __syncthreads();
    #pragma unroll
    for (int rep = 0; rep < 2; ++rep) {
        int idx = t + rep * 256;
        int d = idx >> 3, kc = (idx & 7) * 8;
        short8 o;
        #pragma unroll
        for (int e = 0; e < 8; ++e)
            o[e] = *(const short*)((char*)L + (kc + e) * 128 + ((d * 2) ^ (((kc + e) & 7) << 4)));
        *reinterpret_cast<short8*>(&Vg[((size_t)(bn * 64 + d)) * KLEN + kt * 64 + kc]) = o;
    }
}

// ---------------- bf16 MFMA GEMM (m97 structure, 128x128): small GEMMs -------
template<bool BIAS, bool RELU, bool OUTBF>
__global__ __launch_bounds__(256) void gemm_mfma(
    const u16* __restrict__ A, const u16* __restrict__ BT,
    const float* __restrict__ bias,
    float* __restrict__ Cf, u16* __restrict__ Cb,
    int M, int N, int K, int lda, int ldb)
{
    __shared__ u16 As[128 * 64];
    __shared__ u16 Bs[128 * 64];
    const int bm = blockIdx.y * 128, bn = blockIdx.x * 128;
    const int z = blockIdx.z;
    A  += (size_t)z * K;
    BT += (size_t)z * K;
    const size_t zoff = (size_t)z * M * N;
    const int t = threadIdx.x;
    const int w = t >> 6, l = t & 63, lg = l >> 4, lq = l & 15;
    const int wm = (w >> 1) * 64, wn = (w & 1) * 64;
    const int r8 = l >> 3, slot = l & 7;
    const int gcol = (slot * 16) ^ (r8 << 4);

    f32x4 acc[4][4];
    #pragma unroll
    for (int x = 0; x < 4; ++x)
        #pragma unroll
        for (int y = 0; y < 4; ++y)
            acc[x][y] = (f32x4){0.f, 0.f, 0.f, 0.f};

    const int swzr = (lq & 7) << 4;

    for (int k0 = 0; k0 < K; k0 += 64) {
        __syncthreads();
        #pragma unroll
        for (int it = 0; it < 4; ++it) {
            const int base_row = w * 8 + it * 32;
            gload16((const char*)A + (((size_t)(bm + base_row + r8) * lda + k0) << 1) + gcol,
                    (char*)As + base_row * 128);
            gload16((const char*)BT + (((size_t)(bn + base_row + r8) * ldb + k0) << 1) + gcol,
                    (char*)Bs + base_row * 128);
        }
        __syncthreads();
        #pragma unroll
        for (int ks = 0; ks < 2; ++ks) {
            const int cb = (ks * 64 + 16 * lg) ^ swzr;
            short8 af[4], bf_[4];
            #pragma unroll
            for (int x = 0; x < 4; ++x)
                af[x] = *reinterpret_cast<const short8*>((char*)As + (wm + 16 * x + lq) * 128 + cb);
            #pragma unroll
            for (int y = 0; y < 4; ++y)
                bf_[y] = *reinterpret_cast<const short8*>((char*)Bs + (wn + 16 * y + lq) * 128 + cb);
            #pragma unroll
            for (int x = 0; x < 4; ++x)
                #pragma unroll
                for (int y = 0; y < 4; ++y)
                    acc[x][y] = __builtin_amdgcn_mfma_f32_16x16x32_bf16(af[x], bf_[y], acc[x][y], 0, 0, 0);
        }
    }
    #pragma unroll
    for (int x = 0; x < 4; ++x) {
        #pragma unroll
        for (int y = 0; y < 4; ++y) {
            const int col = bn + wn + 16 * y + lq;
            #pragma unroll
            for (int r = 0; r < 4; ++r) {
                const int row = bm + wm + 16 * x + 4 * lg + r;
                float v = acc[x][y][r];
                if constexpr (BIAS) { if (z == 0) v += bias[col]; }
                if constexpr (RELU) v = fmaxf(v, 0.f);
                if constexpr (OUTBF) Cb[zoff + (size_t)row * N + col] = f2bf(v);
                else                 Cf[zoff + (size_t)row * N + col] = v;
            }
        }
    }
}

// ---------------- deep-pipeline bf16 MFMA GEMM (round-7: 2-phase interleave) -
// BM=256, BN=128, BK=64; 512 threads = 8 waves (4x2), per-wave 64x64.
// 3 LDS buffers, depth-2 prefetch, counted vmcnt(6). Each K-tile = 2 phases:
// {8 ds_read (ks half) || 3 gload (t+2 half) -> barrier -> 16 MFMA}. ds_reads
// are always consumed by MFMA before the next barrier, so no outstanding LDS
// reads exist when buffer (t+2)%3 is overwritten.
template<bool BIAS, bool RELU, bool OUTBF>
__global__ __launch_bounds__(512, 2) void gemm_deep(
    const u16* __restrict__ A, const u16* __restrict__ BT,
    const float* __restrict__ bias,
    float* __restrict__ Cf, u16* __restrict__ Cb,
    int M, int N, int K, int lda, int ldb)
{
    __shared__ u16 lds[3 * 24576];        // 3 x (A 256x64 + B 128x64) = 144 KB
    const int bm = blockIdx.y * 256, bn = blockIdx.x * 128;
    const int z = blockIdx.z;
    A  += (size_t)z * K;
    BT += (size_t)z * K;
    const size_t zoff = (size_t)z * M * N;
    const int t = threadIdx.x;            // 0..511
    const int w = t >> 6, l = t & 63, lg = l >> 4, lq = l & 15;
    const int wm = (w >> 1) * 64;         // 4 M-groups
    const int wn = (w & 1) * 64;          // 2 N-groups
    const int srow = t >> 3, slot = t & 7;
    const int gcol = (slot * 16) ^ ((srow & 7) << 4);
    const int swzr = (lq & 7) << 4;

    // stage one half of K-tile kt into buffer buf: A 2 issues + B 1 issue
    auto stage_half = [&](int kt, int buf, int half) {
        const int k0 = kt * 64;
        char* Ab = (char*)lds + buf * 49152 + w * 1024;
        char* Bb = (char*)lds + buf * 49152 + 32768 + w * 1024;
        #pragma unroll
        for (int i = 0; i < 2; ++i)
            gload16((const char*)A + (((size_t)(bm + (half * 2 + i) * 64 + srow) * lda + k0) << 1) + gcol,
                    Ab + (half * 2 + i) * 8192);
        gload16((const char*)BT + (((size_t)(bn + half * 64 + srow) * ldb + k0) << 1) + gcol,
                Bb + half * 8192);
    };

    f32x4 acc[4][4];
    #pragma unroll
    for (int x = 0; x < 4; ++x)
        #pragma unroll
        for (int y = 0; y < 4; ++y)
            acc[x][y] = (f32x4){0.f, 0.f, 0.f, 0.f};

    const int NT = K >> 6;
    stage_half(0, 0, 0); stage_half(0, 0, 1);
    stage_half(1, 1, 0); stage_half(1, 1, 1);

    for (int kt = 0; kt < NT; ++kt) {
        if (kt < NT - 1) asm volatile("s_waitcnt vmcnt(6)" ::: "memory");
        else             asm volatile("s_waitcnt vmcnt(0)" ::: "memory");
        __builtin_amdgcn_s_barrier();
        __builtin_amdgcn_sched_barrier(0);

        const char* Ab = (const char*)lds + (kt % 3) * 49152;
        const char* Bb = Ab + 32768;
        const bool pf = (kt + 2 < NT);
        const int pbuf = (kt + 2) % 3;

        #pragma unroll
        for (int ks = 0; ks < 2; ++ks) {
            const int cb = (ks * 64 + 16 * lg) ^ swzr;
            short8 af[4], bf_[4];
            #pragma unroll
            for (int x = 0; x < 4; ++x)
                af[x] = *reinterpret_cast<const short8*>(Ab + (wm + 16 * x + lq) * 128 + cb);
            #pragma unroll
            for (int y = 0; y < 4; ++y)
                bf_[y] = *reinterpret_cast<const short8*>(Bb + (wn + 16 * y + lq) * 128 + cb);
            if (pf) stage_half(kt + 2, pbuf, ks);
            if (ks == 0) __builtin_amdgcn_s_barrier();   // phase stagger
            __builtin_amdgcn_s_setprio(1);
            #pragma unroll
            for (int x = 0; x < 4; ++x)
                #pragma unroll
                for (int y = 0; y < 4; ++y)
                    acc[x][y] = __builtin_amdgcn_mfma_f32_16x16x32_bf16(af[x], bf_[y], acc[x][y], 0, 0, 0);
            __builtin_amdgcn_s_setprio(0);
        }
    }

    #pragma unroll
    for (int x = 0; x < 4; ++x) {
        #pragma unroll
        for (int y = 0; y < 4; ++y) {
            const int col = bn + wn + 16 * y + lq;
            #pragma unroll
            for (int r = 0; r < 4; ++r) {
                const int row = bm + wm + 16 * x + 4 * lg + r;
                float v = acc[x][y][r];
                if constexpr (BIAS) { if (z == 0) v += bias[col]; }
                if constexpr (RELU) v = fmaxf(v, 0.f);
                if constexpr (OUTBF) Cb[zoff + (size_t)row * N + col] = f2bf(v);
                else                 Cf[zoff + (size_t)row * N + col] = v;
            }
        }
    }
}

// ---------------- MFMA flash relative attention (round-7) --------------------
// Round-5 structure + (a) defer-max RESCALE_THRESHOLD=8 (skip alpha path when
// per-row max grows <= 8; P bounded by e^8, scale-invariant bf16 precision),
// (b) wave-uniform skip of fully-masked tiles (late tiles, waves 0-3).
__global__ __launch_bounds__(512, 4) void attn_mfma(
    const u16* __restrict__ heads,   // bf16 [KLEN*BSZ][3*NH*DH]
    const u16* __restrict__ Vg,      // bf16 [(b,h)][DH][KLEN]
    const u16* __restrict__ rhk,     // bf16 [KLEN][NH*DH]
    const float* __restrict__ rwb, const float* __restrict__ rrb,
    u16* __restrict__ vec)           // bf16 [QLEN*BSZ][NH*DH]
{
    const int b = blockIdx.x >> 4;
    const int n = blockIdx.x & 15;
    const int i0 = (3 - blockIdx.y) * 128;      // long blocks first
    const int t = threadIdx.x;
    const int w = t >> 6;                        // 0..7
    const int l = t & 63;
    const int lg = l >> 4, lq = l & 15;
    const int r8 = l >> 3, sl = l & 7;

    __shared__ u16 Ks[64 * 64];
    __shared__ u16 Vt[64 * 64];
    __shared__ u16 Rs[192 * 64];
    __shared__ u16 SbO[8 * 16 * 84];
    __shared__ u16 Ps[8 * 16 * 64];

    u16* SbW = SbO + w * 16 * 84;
    u16* PsW = Ps + w * 16 * 64;
    const int swzr = (lq & 7) << 4;
    const int stg_swz = (sl * 16) ^ (r8 << 4);

    short8 qw[2], qr[2];
    {
        const int qrow = i0 + 16 * w + lq;
        const size_t gbase = ((size_t)((MLEN + qrow) * BSZ + b)) * 3072 + n * 64;
        #pragma unroll
        for (int ks = 0; ks < 2; ++ks) {
            short8 qv = *reinterpret_cast<const short8*>(&heads[gbase + ks * 32 + 8 * lg]);
            short8 xw, xr;
            #pragma unroll
            for (int e = 0; e < 8; ++e) {
                float f = bf2f((u16)qv[e]);
                int d = ks * 32 + 8 * lg + e;
                xw[e] = (short)f2bf(f + rwb[n * 64 + d]);
                xr[e] = (short)f2bf(f + rrb[n * 64 + d]);
            }
            qw[ks] = xw; qr[ks] = xr;
        }
    }

    float m_run = NEGF, l_run = 0.f;
    f32x4 acc[4];
    #pragma unroll
    for (int df = 0; df < 4; ++df) acc[df] = (f32x4){0.f, 0.f, 0.f, 0.f};

    const int s0 = 112 - 16 * w;
    const int ntiles = i0 / 64 + 10;

    for (int tile = 0; tile < ntiles; ++tile) {
        const int j0 = tile << 6;
        __syncthreads();
        gload16((const char*)heads
                    + (((size_t)((j0 + w * 8 + r8) * BSZ + b)) * 3072 + 1024 + n * 64) * 2
                    + stg_swz,
                (char*)Ks + w * 1024);
        gload16((const char*)Vg
                    + (((size_t)(blockIdx.x * 64 + w * 8 + r8)) * KLEN + j0) * 2
                    + stg_swz,
                (char*)Vt + w * 1024);
        const int obase = j0 - i0 + 384;
        #pragma unroll
        for (int pass = 0; pass < 3; ++pass) {
            int row = pass * 64 + w * 8 + r8;
            int o = obase + row;
            o = o > (KLEN - 1) ? (KLEN - 1) : o;
            gload16((const char*)rhk + ((size_t)o * 1024 + n * 64) * 2 + stg_swz,
                    (char*)Rs + pass * 8192 + w * 1024);
        }
        __syncthreads();

        // wave-uniform skip: no valid key for any q row of this wave
        const int bmax = i0 + 16 * w + 15 + MLEN - j0;
        if (bmax < 0) continue;     // no barriers inside compute; safe

        __builtin_amdgcn_s_setprio(1);
        #pragma unroll
        for (int ff = 0; ff < 5; ++ff) {
            f32x4 d = (f32x4){0.f, 0.f, 0.f, 0.f};
            #pragma unroll
            for (int ks = 0; ks < 2; ++ks) {
                short8 a = *reinterpret_cast<const short8*>(
                    (char*)Rs + (s0 + 16 * ff + lq) * 128 + ((ks * 64 + 16 * lg) ^ swzr));
                d = __builtin_amdgcn_mfma_f32_16x16x32_bf16(a, qr[ks], d, 0, 0, 0);
            }
            s16x4 pk;
            #pragma unroll
            for (int r = 0; r < 4; ++r) pk[r] = (short)f2bf(d[r]);
            *reinterpret_cast<s16x4*>(&SbW[lq * 84 + 16 * ff + 4 * lg]) = pk;
        }
        f32x4 dac[4];
        #pragma unroll
        for (int f = 0; f < 4; ++f) {
            f32x4 d = (f32x4){0.f, 0.f, 0.f, 0.f};
            #pragma unroll
            for (int ks = 0; ks < 2; ++ks) {
                short8 a = *reinterpret_cast<const short8*>(
                    (char*)Ks + (16 * f + lq) * 128 + ((ks * 64 + 16 * lg) ^ swzr));
                d = __builtin_amdgcn_mfma_f32_16x16x32_bf16(a, qw[ks], d, 0, 0, 0);
            }
            dac[f] = d;
        }
        __builtin_amdgcn_s_setprio(0);

        const bool fullTile = (i0 + 16 * w + MLEN - j0) >= 63;
        float sv[4][4];
        float mx = NEGF;
        if (fullTile) {
            #pragma unroll
            for (int f = 0; f < 4; ++f)
                #pragma unroll
                for (int r = 0; r < 4; ++r) {
                    int k = 16 * f + 4 * lg + r;
                    float bd = bf2f(SbW[lq * 84 + k - lq + 15]);
                    float x = (dac[f][r] + bd) * 0.125f;
                    sv[f][r] = x;
                    mx = fmaxf(mx, x);
                }
        } else {
            const int bound = i0 + 16 * w + lq + MLEN - j0;
            #pragma unroll
            for (int f = 0; f < 4; ++f)
                #pragma unroll
                for (int r = 0; r < 4; ++r) {
                    int k = 16 * f + 4 * lg + r;
                    float bd = bf2f(SbW[lq * 84 + k - lq + 15]);
                    float x = (k <= bound) ? (dac[f][r] + bd) * 0.125f : NEGF;
                    sv[f][r] = x;
                    mx = fmaxf(mx, x);
                }
        }
        mx = fmaxf(mx, __shfl_xor(mx, 16));
        mx = fmaxf(mx, __shfl_xor(mx, 32));
        // T13 defer-max: keep old running max when growth <= 8 (wave-uniform)
        const bool defer = (__all(mx <= m_run + 8.0f) != 0);
        const float m_new = defer ? m_run : fmaxf(m_run, mx);
        float ps = 0.f;
        #pragma unroll
        for (int f = 0; f < 4; ++f) {
            s16x4 pk;
            #pragma unroll
            for (int r = 0; r < 4; ++r) {
                float p = __expf(sv[f][r] - m_new);
                ps += p;
                pk[r] = (short)f2bf(p);
            }
            *reinterpret_cast<s16x4*>(
                (char*)PsW + lq * 128 + (((4 * f + lg) ^ ((lq & 7) << 1)) << 3)) = pk;
        }
        ps += __shfl_xor(ps, 16);
        ps += __shfl_xor(ps, 32);
        if (defer) {
            l_run += ps;
        } else {
            float alpha = __expf(m_run - m_new);
            l_run = l_run * alpha + ps;
            m_run = m_new;
            float alr[4];
            #pragma unroll
            for (int r = 0; r < 4; ++r) alr[r] = __shfl(alpha, 20 * lg + r);
            #pragma unroll
            for (int df = 0; df < 4; ++df)
                #pragma unroll
                for (int r = 0; r < 4; ++r) acc[df][r] *= alr[r];
        }

        __builtin_amdgcn_s_setprio(1);
        #pragma unroll
        for (int df = 0; df < 4; ++df) {
            f32x4 a = acc[df];
            #pragma unroll
            for (int ks = 0; ks < 2; ++ks) {
                short8 pa = *reinterpret_cast<const short8*>(
                    (char*)PsW + lq * 128 + ((ks * 64 + 16 * lg) ^ swzr));
                short8 vb = *reinterpret_cast<const short8*>(
                    (char*)Vt + (16 * df + lq) * 128 + ((ks * 64 + 16 * lg) ^ swzr));
                a = __builtin_amdgcn_mfma_f32_16x16x32_bf16(pa, vb, a, 0, 0, 0);
            }
            acc[df] = a;
        }
        __builtin_amdgcn_s_setprio(0);
    }

    float inv[4];
    #pragma unroll
    for (int r = 0; r < 4; ++r) inv[r] = 1.f / __shfl(l_run, 20 * lg + r);
    #pragma unroll
    for (int df = 0; df < 4; ++df) {
        #pragma unroll
        for (int r = 0; r < 4; ++r) {
            const int il = 16 * w + 4 * lg + r;
            float o = acc[df][r] * inv[r];
            vec[((size_t)((i0 + il) * BSZ + b)) * DM + n * 64 + 16 * df + lq] = f2bf(o);
        }
    }
}

// ---------------- Residual + LayerNorm (1 or 2 extra residual streams) -------
template<int NRES, bool WB>
__global__ __launch_bounds__(256) void ln_res_kernel(
    const float* __restrict__ x, const float* __restrict__ res,
    const float* __restrict__ res2,
    const float* __restrict__ g, const float* __restrict__ bta,
    float* __restrict__ out, u16* __restrict__ outb)
{
    const int row = blockIdx.x;
    const int t = threadIdx.x;
    const int lane = t & 63, wv = t >> 6;
    __shared__ float red0[4], red1[4];

    float4 a = ldg4(&x[(size_t)row * DM + t * 4]);
    float4 b = ldg4(&res[(size_t)row * DM + t * 4]);
    float v0 = a.x + b.x, v1 = a.y + b.y, v2 = a.z + b.z, v3 = a.w + b.w;
    if constexpr (NRES == 2) {
        float4 c = ldg4(&res2[(size_t)row * DM + t * 4]);
        v0 += c.x; v1 += c.y; v2 += c.z; v3 += c.w;
    }
    float s = v0 + v1 + v2 + v3;
    #pragma unroll
    for (int o = 32; o; o >>= 1) s += __shfl_xor(s, o);
    if (lane == 0) red0[wv] = s;
    __syncthreads();
    float mu = (red0[0] + red0[1] + red0[2] + red0[3]) * (1.f / DM);
    float d0 = v0 - mu, d1 = v1 - mu, d2 = v2 - mu, d3 = v3 - mu;
    float q = d0*d0 + d1*d1 + d2*d2 + d3*d3;
    #pragma unroll
    for (int o = 32; o; o >>= 1) q += __shfl_xor(q, o);
    if (lane == 0) red1[wv] = q;
    __syncthreads();
    float var = (red1[0] + red1[1] + red1[2] + red1[3]) * (1.f / DM);
    float rs = rsqrtf(var + 1e-5f);
    float4 gv = ldg4(&g[t * 4]);
    float4 bv = ldg4(&bta[t * 4]);
    float o0 = d0 * rs * gv.x + bv.x;
    float o1 = d1 * rs * gv.y + bv.y;
    float o2 = d2 * rs * gv.z + bv.z;
    float o3 = d3 * rs * gv.w + bv.w;
    float4 o4 = make_float4(o0, o1, o2, o3);
    *reinterpret_cast<float4*>(&out[(size_t)row * DM + t * 4]) = o4;
    if constexpr (WB) {
        u16 ob[4] = { f2bf(o0), f2bf(o1), f2bf(o2), f2bf(o3) };
        *reinterpret_cast<uint2*>(&outb[(size_t)row * DM + t * 4]) = *reinterpret_cast<uint2*>(ob);
    }
}

// ---------------- launch ------------------------------------------------------
extern "C" void kernel_launch(void* const* d_in, const int* in_sizes, int n_in,
                              void* d_out, int out_size, void* d_ws, size_t ws_size,
                              hipStream_t stream) {
    const float* w     = (const float*)d_in[0];
    const float* r     = (const float*)d_in[1];
    const float* mems  = (const float*)d_in[2];
    const float* w_qkv = (const float*)d_in[3];
    const float* w_r   = (const float*)d_in[4];
    const float* w_o   = (const float*)d_in[5];
    const float* rwb   = (const float*)d_in[6];
    const float* rrb   = (const float*)d_in[7];
    const float* ln1g  = (const float*)d_in[8];
    const float* ln1b  = (const float*)d_in[9];
    const float* ffw1  = (const float*)d_in[10];
    const float* ffb1  = (const float*)d_in[11];
    const float* ffw2  = (const float*)d_in[12];
    const float* ffb2  = (const float*)d_in[13];
    const float* ln2g  = (const float*)d_in[14];
    const float* ln2b  = (const float*)d_in[15];
    (void)in_sizes; (void)n_in; (void)out_size; (void)ws_size;

    char* p = (char*)d_ws;
    auto alloc = [&](size_t bytes) { char* q = p; p += (bytes + 255) & ~(size_t)255; return q; };
    u16* catB   = (u16*)alloc((size_t)8192 * 1024 * 2);   // reused as Vg after QKV GEMM
    u16* rB     = (u16*)alloc((size_t)1024 * 1024 * 2);
    u16* qkvT   = (u16*)alloc((size_t)3072 * 1024 * 2);
    u16* wrT    = (u16*)alloc((size_t)1024 * 1024 * 2);
    u16* woT    = (u16*)alloc((size_t)1024 * 1024 * 2);
    u16* f1T    = (u16*)alloc((size_t)4096 * 1024 * 2);
    u16* f2T    = (u16*)alloc((size_t)1024 * 4096 * 2);
    u16* heads  = (u16*)alloc((size_t)8192 * 3072 * 2);   // reused as ff2[2] after attn
    u16* rhk    = (u16*)alloc((size_t)1024 * 1024 * 2);
    u16* vec    = (u16*)alloc((size_t)4096 * 1024 * 2);
    u16* hB     = (u16*)alloc((size_t)4096 * 1024 * 2);
    u16* ff1    = (u16*)alloc((size_t)4096 * 4096 * 2);   // doubles as attn_out[2] before ff1
    float* hF   = (float*)alloc((size_t)4096 * 1024 * 4);

    u16* Vg = catB;
    float* attn_out = (float*)ff1;
    float* ff2 = (float*)heads;
    float* outp = (float*)d_out;

    // casts + fused weight transposes
    cast2_kernel<<<8192, 256, 0, stream>>>(mems, w, 4096 * 1024, catB, 8192 * 1024);
    cast2_kernel<<<1024, 256, 0, stream>>>(r, r, 1024 * 1024, rB, 1024 * 1024);
    transpose_all<<<13312, 256, 0, stream>>>(w_qkv, qkvT, w_r, wrT, w_o, woT,
                                             ffw1, f1T, ffw2, f2T);

    // 1. heads = cat @ w_qkv  (deep pipeline: M=8192, N=3072, K=1024)
    gemm_deep<false, false, true><<<dim3(24, 32), 512, 0, stream>>>(
        catB, qkvT, nullptr, nullptr, heads, 8192, 3072, 1024, 1024, 1024);
    // 2. V transpose (catB dead -> Vg aliases it)
    v_transpose<<<dim3(128, 16), 256, 0, stream>>>(heads, Vg);
    // 3. rhk = r @ w_r (small: keep 128^2 kernel)
    gemm_mfma<false, false, true><<<dim3(8, 8), 256, 0, stream>>>(
        rB, wrT, nullptr, nullptr, rhk, 1024, 1024, 1024, 1024, 1024);
    // 4. attention
    attn_mfma<<<dim3(BSZ * NH, QLEN / 128), 512, 0, stream>>>(
        heads, Vg, rhk, rwb, rrb, vec);
    // 5. attn_out = vec @ w_o, split-K x2 (128^2 kernel: better grid fit)
    gemm_mfma<false, false, false><<<dim3(8, 32, 2), 256, 0, stream>>>(
        vec, woT, nullptr, attn_out, nullptr, 4096, 1024, 512, 1024, 1024);
    // 6. h = LN(w + ao0 + ao1), keep fp32 + bf16
    ln_res_kernel<2, true><<<4096, 256, 0, stream>>>(
        w, attn_out, attn_out + (size_t)4096 * 1024, ln1g, ln1b, hF, hB);
    // 7. ff1 = relu(h @ ff_w1 + b1)  (deep pipeline: 4096x4096x1024)
    gemm_deep<true, true, true><<<dim3(32, 16), 512, 0, stream>>>(
        hB, f1T, ffb1, nullptr, ff1, 4096, 4096, 1024, 1024, 1024);
    // 8. ff2 = ff1 @ ff_w2 + b2, split-K x2 (deep pipeline: 4096x1024x2048 each)
    gemm_deep<true, false, false><<<dim3(8, 16, 2), 512, 0, stream>>>(
        ff1, f2T, ffb2, ff2, nullptr, 4096, 1024, 2048, 4096, 4096);
    // 9. out = LN(h + ff2a + ff2b)
    ln_res_kernel<2, false><<<4096, 256, 0, stream>>>(
        hF, ff2, ff2 + (size_t)4096 * 1024, ln2g, ln2b, outp, nullptr);
}